// Round 2
// baseline (8443.604 us; speedup 1.0000x reference)
//
#include <hip/hip_runtime.h>
#include <hip/hip_bf16.h>

#define NTOK 4096
#define DEMB 1024
#define NH   8
#define DH   128
#define CWIN 256
#define QKVW 384           // 3*DH
#define SCALE 0.08838834764831845f   // 1/sqrt(128)

// ---------------- reductions (256-thread block, 4 waves) ----------------
__device__ __forceinline__ float block_sum(float v, float* red) {
    #pragma unroll
    for (int o = 32; o > 0; o >>= 1) v += __shfl_down(v, o, 64);
    __syncthreads();                       // protect red from previous use
    int lane = threadIdx.x & 63, wv = threadIdx.x >> 6;
    if (lane == 0) red[wv] = v;
    __syncthreads();
    return red[0] + red[1] + red[2] + red[3];
}

__device__ __forceinline__ float block_max(float v, float* red) {
    #pragma unroll
    for (int o = 32; o > 0; o >>= 1) v = fmaxf(v, __shfl_down(v, o, 64));
    __syncthreads();
    int lane = threadIdx.x & 63, wv = threadIdx.x >> 6;
    if (lane == 0) red[wv] = v;
    __syncthreads();
    return fmaxf(fmaxf(red[0], red[1]), fmaxf(red[2], red[3]));
}

// ---------------- stage 0: e = x (fp32 copy; e is mutated across heads) ---
__global__ void init_e(const float4* __restrict__ x, float4* __restrict__ e) {
    int i = blockIdx.x * 256 + threadIdx.x;
    e[i] = x[i];
}

// ---------------- stage 1: qkv = e @ [Wq;Wk;Wvd]^T  (fp32) ----------------
// grid (6, 64), block 256. Tile 64x64, BK=16, 4x4 per thread.
__global__ void qkv_gemm(const float* __restrict__ e,
                         const float* __restrict__ Wq,
                         const float* __restrict__ Wk,
                         const float* __restrict__ Wvd,
                         float* __restrict__ qkv, int head) {
    const int c0 = blockIdx.x * 64;        // output col tile [c0, c0+64)
    const int r0 = blockIdx.y * 64;        // output row tile
    const float* bases[3] = {Wq, Wk, Wvd};
    const float* W = bases[c0 >> 7]
        + (size_t)head * DH * DEMB + (size_t)(c0 & 127) * DEMB;

    __shared__ float As[64][17];
    __shared__ float Bs[64][17];
    const int tid = threadIdx.x;
    const int tx = tid & 15, ty = tid >> 4;

    float acc[4][4] = {};
    for (int k0 = 0; k0 < DEMB; k0 += 16) {
        #pragma unroll
        for (int i = 0; i < 4; i++) {
            int f = tid * 4 + i;
            int r = f >> 4, kk = f & 15;
            As[r][kk] = e[(size_t)(r0 + r) * DEMB + k0 + kk];
            Bs[r][kk] = W[(size_t)r * DEMB + k0 + kk];
        }
        __syncthreads();
        #pragma unroll
        for (int kk = 0; kk < 16; kk++) {
            float a[4], b[4];
            #pragma unroll
            for (int i = 0; i < 4; i++) a[i] = As[ty * 4 + i][kk];
            #pragma unroll
            for (int i = 0; i < 4; i++) b[i] = Bs[tx * 4 + i][kk];
            #pragma unroll
            for (int i = 0; i < 4; i++)
                #pragma unroll
                for (int j = 0; j < 4; j++) acc[i][j] += a[i] * b[j];
        }
        __syncthreads();
    }
    #pragma unroll
    for (int i = 0; i < 4; i++)
        #pragma unroll
        for (int j = 0; j < 4; j++)
            qkv[(size_t)(r0 + ty * 4 + i) * QKVW + c0 + tx * 4 + j] = acc[i][j];
}

// ---------------- stage 2: banded attention, one block per query row ------
__global__ void attn_row(const float* __restrict__ qkv, float* __restrict__ u) {
    const int j = blockIdx.x;
    const int tid = threadIdx.x;           // 256
    const int t0 = max(j - CWIN, 0);
    const int t1 = min(j + CWIN, NTOK);
    const int wlen = t1 - t0;

    __shared__ float qs[DH];
    __shared__ float sc[2 * CWIN];
    __shared__ float red[4];

    if (tid < DH) qs[tid] = qkv[(size_t)j * QKVW + tid];
    __syncthreads();

    // scores
    for (int t = tid; t < wlen; t += 256) {
        const float4* k4 = (const float4*)(qkv + (size_t)(t0 + t) * QKVW + DH);
        float s = 0.f;
        #pragma unroll
        for (int d4 = 0; d4 < DH / 4; d4++) {
            float4 kv = k4[d4];
            s += qs[d4 * 4 + 0] * kv.x + qs[d4 * 4 + 1] * kv.y
               + qs[d4 * 4 + 2] * kv.z + qs[d4 * 4 + 3] * kv.w;
        }
        sc[t] = s * SCALE;
    }
    __syncthreads();

    float m = -INFINITY;
    for (int t = tid; t < wlen; t += 256) m = fmaxf(m, sc[t]);
    m = block_max(m, red);

    float lsum = 0.f;
    for (int t = tid; t < wlen; t += 256) {
        float p = __expf(sc[t] - m);
        sc[t] = p;
        lsum += p;
    }
    float denom = block_sum(lsum, red);
    __syncthreads();

    if (tid < DH) {
        float acc = 0.f;
        const float* vbase = qkv + (size_t)t0 * QKVW + 2 * DH + tid;
        for (int t = 0; t < wlen; t++) acc += sc[t] * vbase[(size_t)t * QKVW];
        u[(size_t)j * DH + tid] = acc / denom;
    }
}

// ---------------- stage 3: delta = u @ Wvu^T, residual + double-norm ------
__global__ void proj_norm(const float* __restrict__ u,
                          const float* __restrict__ Wvu,  // [DEMB, DH] for this head
                          float* __restrict__ e) {
    const int j = blockIdx.x;
    const int tid = threadIdx.x;           // 256, each owns d = tid + 256*i
    __shared__ float us[DH];
    __shared__ float red[4];
    if (tid < DH) us[tid] = u[(size_t)j * DH + tid];
    __syncthreads();

    float eo[4], out[4];
    #pragma unroll
    for (int i = 0; i < 4; i++) {
        const int d = tid + 256 * i;
        const float4* wr = (const float4*)(Wvu + (size_t)d * DH);
        float acc = 0.f;
        #pragma unroll 8
        for (int c4 = 0; c4 < DH / 4; c4++) {
            float4 w = wr[c4];
            acc += us[c4 * 4 + 0] * w.x + us[c4 * 4 + 1] * w.y
                 + us[c4 * 4 + 2] * w.z + us[c4 * 4 + 3] * w.w;
        }
        eo[i] = e[(size_t)j * DEMB + d];
        out[i] = eo[i] + acc;
    }

    float s = out[0] + out[1] + out[2] + out[3];
    float m0 = block_sum(s, red) * (1.0f / DEMB);
    float inv_m0 = 1.0f / m0;
    #pragma unroll
    for (int i = 0; i < 4; i++) out[i] *= inv_m0;

    s = out[0] + out[1] + out[2] + out[3];
    float m = block_sum(s, red) * (1.0f / DEMB);

    float v = 0.f;
    #pragma unroll
    for (int i = 0; i < 4; i++) { float dd = out[i] - m; v += dd * dd; }
    float var = block_sum(v, red) * (1.0f / (DEMB - 1));
    float inv_sd = rsqrtf(var);

    #pragma unroll
    for (int i = 0; i < 4; i++) {
        const int d = tid + 256 * i;
        float h = (out[i] - m) * inv_sd + m;
        e[(size_t)j * DEMB + d] = eo[i] + h;
    }
}

// ---------------- stage 4: out = e / H ----------------
__global__ void final_scale(const float* __restrict__ e, float* __restrict__ out) {
    int i = blockIdx.x * 256 + threadIdx.x;
    out[i] = e[i] * (1.0f / NH);
}

extern "C" void kernel_launch(void* const* d_in, const int* in_sizes, int n_in,
                              void* d_out, int out_size, void* d_ws, size_t ws_size,
                              hipStream_t stream) {
    const float* x   = (const float*)d_in[0];
    const float* Wq  = (const float*)d_in[1];
    const float* Wk  = (const float*)d_in[2];
    const float* Wvd = (const float*)d_in[3];
    const float* Wvu = (const float*)d_in[4];
    float* out = (float*)d_out;

    float* e   = (float*)d_ws;                 // [NTOK, DEMB]
    float* qkv = e + (size_t)NTOK * DEMB;      // [NTOK, 384]
    float* u   = qkv + (size_t)NTOK * QKVW;    // [NTOK, DH]

    init_e<<<NTOK * DEMB / 4 / 256, 256, 0, stream>>>((const float4*)x, (float4*)e);

    for (int h = 0; h < NH; h++) {
        qkv_gemm<<<dim3(QKVW / 64, NTOK / 64), 256, 0, stream>>>(e, Wq, Wk, Wvd, qkv, h);
        attn_row<<<NTOK, 256, 0, stream>>>(qkv, u);
        proj_norm<<<NTOK, 256, 0, stream>>>(u, Wvu + (size_t)h * DEMB * DH, e);
    }

    final_scale<<<NTOK * DEMB / 256, 256, 0, stream>>>(e, out);
}

// Round 3
// 2255.540 us; speedup vs baseline: 3.7435x; 3.7435x over previous
//
#include <hip/hip_runtime.h>
#include <hip/hip_bf16.h>

#define NTOK 4096
#define DEMB 1024
#define NH   8
#define DH   128
#define CWIN 256
#define QKVW 384           // 3*DH
#define SCALE 0.08838834764831845f   // 1/sqrt(128)
#define QT 16              // queries per attention block
#define KT 64              // key tile

// ---------------- reductions (256-thread block, 4 waves) ----------------
__device__ __forceinline__ float block_sum(float v, float* red) {
    #pragma unroll
    for (int o = 32; o > 0; o >>= 1) v += __shfl_down(v, o, 64);
    __syncthreads();
    int lane = threadIdx.x & 63, wv = threadIdx.x >> 6;
    if (lane == 0) red[wv] = v;
    __syncthreads();
    return red[0] + red[1] + red[2] + red[3];
}

// ---------------- stage 0: e = x ----------------
__global__ void init_e(const float4* __restrict__ x, float4* __restrict__ e) {
    int i = blockIdx.x * 256 + threadIdx.x;
    e[i] = x[i];
}

// ---------------- stage 1: qkv = e @ [Wq;Wk;Wvd]^T  (fp32) ----------------
__global__ void qkv_gemm(const float* __restrict__ e,
                         const float* __restrict__ Wq,
                         const float* __restrict__ Wk,
                         const float* __restrict__ Wvd,
                         float* __restrict__ qkv, int head) {
    const int c0 = blockIdx.x * 64;
    const int r0 = blockIdx.y * 64;
    const float* bases[3] = {Wq, Wk, Wvd};
    const float* W = bases[c0 >> 7]
        + (size_t)head * DH * DEMB + (size_t)(c0 & 127) * DEMB;

    __shared__ float As[64][17];
    __shared__ float Bs[64][17];
    const int tid = threadIdx.x;
    const int tx = tid & 15, ty = tid >> 4;

    float acc[4][4] = {};
    for (int k0 = 0; k0 < DEMB; k0 += 16) {
        #pragma unroll
        for (int i = 0; i < 4; i++) {
            int f = tid * 4 + i;
            int r = f >> 4, kk = f & 15;
            As[r][kk] = e[(size_t)(r0 + r) * DEMB + k0 + kk];
            Bs[r][kk] = W[(size_t)r * DEMB + k0 + kk];
        }
        __syncthreads();
        #pragma unroll
        for (int kk = 0; kk < 16; kk++) {
            float a[4], b[4];
            #pragma unroll
            for (int i = 0; i < 4; i++) a[i] = As[ty * 4 + i][kk];
            #pragma unroll
            for (int i = 0; i < 4; i++) b[i] = Bs[tx * 4 + i][kk];
            #pragma unroll
            for (int i = 0; i < 4; i++)
                #pragma unroll
                for (int j = 0; j < 4; j++) acc[i][j] += a[i] * b[j];
        }
        __syncthreads();
    }
    #pragma unroll
    for (int i = 0; i < 4; i++)
        #pragma unroll
        for (int j = 0; j < 4; j++)
            qkv[(size_t)(r0 + ty * 4 + i) * QKVW + c0 + tx * 4 + j] = acc[i][j];
}

// ---------------- stage 2: flash-style banded attention -------------------
// grid 256 blocks (16 queries each), 256 threads. K/V tiles staged in LDS.
// thread (ty,tx): ty = query row, tx covers keys {tx+16c} / dims {tx+16i}.
__global__ __launch_bounds__(256) void attn_tile(const float* __restrict__ qkv,
                                                 float* __restrict__ u) {
    const int q0 = blockIdx.x * QT;
    const int tid = threadIdx.x;
    const int ty = tid >> 4, tx = tid & 15;

    __shared__ float Qs[QT][DH];          // pre-scaled by SCALE
    __shared__ float Ks[KT][DH + 4];      // +4 pad: break stride-128 conflicts
    __shared__ float Vs[KT][DH + 4];
    __shared__ float Ps[QT][KT + 1];

    // load+scale Q tile (16x128 = 512 float4)
    #pragma unroll
    for (int i = 0; i < 2; i++) {
        int idx = tid + 256 * i;
        int r = idx >> 5, c4 = idx & 31;
        float4 qv = *(const float4*)(qkv + (size_t)(q0 + r) * QKVW + c4 * 4);
        qv.x *= SCALE; qv.y *= SCALE; qv.z *= SCALE; qv.w *= SCALE;
        *(float4*)&Qs[r][c4 * 4] = qv;
    }

    const int qg = q0 + ty;
    const int kstart = max(q0 - CWIN, 0);
    const int kend   = min(q0 + QT - 1 + CWIN + 1, NTOK);

    float mrow = -1e30f, lrow = 0.f;
    float O[8] = {};

    for (int kt = kstart; kt < kend; kt += KT) {
        __syncthreads();                  // previous tile's LDS reads done
        // stage K/V tile (each matrix: 2048 float4, 8 per thread)
        #pragma unroll
        for (int i = 0; i < 8; i++) {
            int idx = tid + 256 * i;
            int r = idx >> 5, c4 = idx & 31;
            int t = kt + r;
            float4 kv = make_float4(0.f, 0.f, 0.f, 0.f), vv = kv;
            if (t < kend) {
                kv = *(const float4*)(qkv + (size_t)t * QKVW + DH + c4 * 4);
                vv = *(const float4*)(qkv + (size_t)t * QKVW + 2 * DH + c4 * 4);
            }
            *(float4*)&Ks[r][c4 * 4] = kv;
            *(float4*)&Vs[r][c4 * 4] = vv;
        }
        __syncthreads();

        // scores for row ty, cols {tx+16c}
        float acc[4] = {0.f, 0.f, 0.f, 0.f};
        const float4* q4 = (const float4*)&Qs[ty][0];
        #pragma unroll 8
        for (int d4 = 0; d4 < DH / 4; d4++) {
            float4 qv = q4[d4];
            #pragma unroll
            for (int c = 0; c < 4; c++) {
                float4 kv = *(const float4*)&Ks[tx + 16 * c][d4 * 4];
                acc[c] += qv.x * kv.x + qv.y * kv.y + qv.z * kv.z + qv.w * kv.w;
            }
        }
        bool val[4];
        #pragma unroll
        for (int c = 0; c < 4; c++) {
            int t = kt + tx + 16 * c;
            val[c] = (t < kend) && (t >= qg - CWIN) && (t < qg + CWIN);
            Ps[ty][tx + 16 * c] = val[c] ? acc[c] : -1e30f;
        }
        __syncthreads();

        // row max (redundant across the 16 tx threads; broadcast reads)
        float tmax = -1e30f;
        #pragma unroll 8
        for (int k = 0; k < KT; k++) tmax = fmaxf(tmax, Ps[ty][k]);
        float mnew = fmaxf(mrow, tmax);
        float alpha = __expf(mrow - mnew);
        __syncthreads();                  // raw-score scans done before overwrite

        // exponentiate own cols (from registers)
        #pragma unroll
        for (int c = 0; c < 4; c++)
            Ps[ty][tx + 16 * c] = val[c] ? __expf(acc[c] - mnew) : 0.f;
        __syncthreads();

        float psum = 0.f;
        #pragma unroll 8
        for (int k = 0; k < KT; k++) psum += Ps[ty][k];
        lrow = alpha * lrow + psum;
        mrow = mnew;
        #pragma unroll
        for (int i = 0; i < 8; i++) O[i] *= alpha;

        // O += P @ V
        #pragma unroll 8
        for (int k = 0; k < KT; k++) {
            float p = Ps[ty][k];
            #pragma unroll
            for (int i = 0; i < 8; i++) O[i] += p * Vs[k][tx + 16 * i];
        }
    }

    float invl = 1.0f / lrow;
    #pragma unroll
    for (int i = 0; i < 8; i++)
        u[(size_t)qg * DH + tx + 16 * i] = O[i] * invl;
}

// ---------------- stage 3a: delta = u @ Wvu^T (tiled GEMM) ----------------
// grid (16, 64): 64x64 output tile, K=128 staged fully in LDS.
__global__ __launch_bounds__(256) void delta_gemm(const float* __restrict__ u,
                                                  const float* __restrict__ Wvu,
                                                  float* __restrict__ delta) {
    const int c0 = blockIdx.x * 64, r0 = blockIdx.y * 64;
    const int tid = threadIdx.x, ty = tid >> 4, tx = tid & 15;
    __shared__ float Us[64][DH + 4];
    __shared__ float Ws[64][DH + 4];
    #pragma unroll
    for (int i = 0; i < 8; i++) {
        int idx = tid + 256 * i, r = idx >> 5, c4 = idx & 31;
        *(float4*)&Us[r][c4 * 4] = *(const float4*)(u   + (size_t)(r0 + r) * DH + c4 * 4);
        *(float4*)&Ws[r][c4 * 4] = *(const float4*)(Wvu + (size_t)(c0 + r) * DH + c4 * 4);
    }
    __syncthreads();
    float acc[4][4] = {};
    #pragma unroll 4
    for (int d4 = 0; d4 < DH / 4; d4++) {
        float4 a[4], b[4];
        #pragma unroll
        for (int i = 0; i < 4; i++) a[i] = *(const float4*)&Us[ty + 16 * i][d4 * 4];
        #pragma unroll
        for (int j = 0; j < 4; j++) b[j] = *(const float4*)&Ws[tx + 16 * j][d4 * 4];
        #pragma unroll
        for (int i = 0; i < 4; i++)
            #pragma unroll
            for (int j = 0; j < 4; j++)
                acc[i][j] += a[i].x * b[j].x + a[i].y * b[j].y
                           + a[i].z * b[j].z + a[i].w * b[j].w;
    }
    #pragma unroll
    for (int i = 0; i < 4; i++)
        #pragma unroll
        for (int j = 0; j < 4; j++)
            delta[(size_t)(r0 + ty + 16 * i) * DEMB + c0 + tx + 16 * j] = acc[i][j];
}

// ---------------- stage 3b: residual + double-norm ------------------------
__global__ __launch_bounds__(256) void norm_row(const float* __restrict__ delta,
                                                float* __restrict__ e) {
    const int j = blockIdx.x, tid = threadIdx.x;
    __shared__ float red[4];
    float4 eo = ((const float4*)e)[(size_t)j * 256 + tid];
    float4 dd = ((const float4*)delta)[(size_t)j * 256 + tid];
    float4 out = make_float4(eo.x + dd.x, eo.y + dd.y, eo.z + dd.z, eo.w + dd.w);

    float m0 = block_sum(out.x + out.y + out.z + out.w, red) * (1.0f / DEMB);
    float inv_m0 = 1.0f / m0;
    out.x *= inv_m0; out.y *= inv_m0; out.z *= inv_m0; out.w *= inv_m0;

    float m = block_sum(out.x + out.y + out.z + out.w, red) * (1.0f / DEMB);

    float dx = out.x - m, dy = out.y - m, dz = out.z - m, dw = out.w - m;
    float var = block_sum(dx * dx + dy * dy + dz * dz + dw * dw, red)
              * (1.0f / (DEMB - 1));
    float inv_sd = rsqrtf(var);

    float4 res;
    res.x = eo.x + dx * inv_sd + m;
    res.y = eo.y + dy * inv_sd + m;
    res.z = eo.z + dz * inv_sd + m;
    res.w = eo.w + dw * inv_sd + m;
    ((float4*)e)[(size_t)j * 256 + tid] = res;
}

// ---------------- fallback fused proj+norm (if ws too small) --------------
__global__ void proj_norm(const float* __restrict__ u,
                          const float* __restrict__ Wvu,
                          float* __restrict__ e) {
    const int j = blockIdx.x;
    const int tid = threadIdx.x;
    __shared__ float us[DH];
    __shared__ float red[4];
    if (tid < DH) us[tid] = u[(size_t)j * DH + tid];
    __syncthreads();

    float eo[4], out[4];
    #pragma unroll
    for (int i = 0; i < 4; i++) {
        const int d = tid + 256 * i;
        const float4* wr = (const float4*)(Wvu + (size_t)d * DH);
        float acc = 0.f;
        #pragma unroll 8
        for (int c4 = 0; c4 < DH / 4; c4++) {
            float4 w = wr[c4];
            acc += us[c4 * 4 + 0] * w.x + us[c4 * 4 + 1] * w.y
                 + us[c4 * 4 + 2] * w.z + us[c4 * 4 + 3] * w.w;
        }
        eo[i] = e[(size_t)j * DEMB + d];
        out[i] = eo[i] + acc;
    }
    float s = out[0] + out[1] + out[2] + out[3];
    float m0 = block_sum(s, red) * (1.0f / DEMB);
    float inv_m0 = 1.0f / m0;
    #pragma unroll
    for (int i = 0; i < 4; i++) out[i] *= inv_m0;
    s = out[0] + out[1] + out[2] + out[3];
    float m = block_sum(s, red) * (1.0f / DEMB);
    float v = 0.f;
    #pragma unroll
    for (int i = 0; i < 4; i++) { float dd = out[i] - m; v += dd * dd; }
    float var = block_sum(v, red) * (1.0f / (DEMB - 1));
    float inv_sd = rsqrtf(var);
    #pragma unroll
    for (int i = 0; i < 4; i++) {
        const int d = tid + 256 * i;
        e[(size_t)j * DEMB + d] = eo[i] + (out[i] - m) * inv_sd + m;
    }
}

// ---------------- stage 4: out = e / H ----------------
__global__ void final_scale(const float* __restrict__ e, float* __restrict__ out) {
    int i = blockIdx.x * 256 + threadIdx.x;
    out[i] = e[i] * (1.0f / NH);
}

extern "C" void kernel_launch(void* const* d_in, const int* in_sizes, int n_in,
                              void* d_out, int out_size, void* d_ws, size_t ws_size,
                              hipStream_t stream) {
    const float* x   = (const float*)d_in[0];
    const float* Wq  = (const float*)d_in[1];
    const float* Wk  = (const float*)d_in[2];
    const float* Wvd = (const float*)d_in[3];
    const float* Wvu = (const float*)d_in[4];
    float* out = (float*)d_out;

    float* e     = (float*)d_ws;                  // [4096,1024] 16 MB
    float* qkv   = e + (size_t)NTOK * DEMB;       // [4096, 384]  6 MB
    float* u     = qkv + (size_t)NTOK * QKVW;     // [4096, 128]  2 MB
    float* delta = u + (size_t)NTOK * DH;         // [4096,1024] 16 MB
    const size_t ws_needed = ((size_t)NTOK * DEMB * 2 + (size_t)NTOK * QKVW
                              + (size_t)NTOK * DH) * sizeof(float);
    const bool use_delta = ws_size >= ws_needed;

    init_e<<<NTOK * DEMB / 4 / 256, 256, 0, stream>>>((const float4*)x, (float4*)e);

    for (int h = 0; h < NH; h++) {
        qkv_gemm<<<dim3(QKVW / 64, NTOK / 64), 256, 0, stream>>>(e, Wq, Wk, Wvd, qkv, h);
        attn_tile<<<NTOK / QT, 256, 0, stream>>>(qkv, u);
        const float* Wvu_h = Wvu + (size_t)h * DEMB * DH;
        if (use_delta) {
            delta_gemm<<<dim3(DEMB / 64, NTOK / 64), 256, 0, stream>>>(u, Wvu_h, delta);
            norm_row<<<NTOK, 256, 0, stream>>>(delta, e);
        } else {
            proj_norm<<<NTOK, 256, 0, stream>>>(u, Wvu_h, e);
        }
    }

    final_scale<<<NTOK * DEMB / 256, 256, 0, stream>>>(e, out);
}

// Round 4
// 1126.364 us; speedup vs baseline: 7.4963x; 2.0025x over previous
//
#include <hip/hip_runtime.h>
#include <hip/hip_bf16.h>

#define NTOK 4096
#define DEMB 1024
#define NH   8
#define DH   128
#define CWIN 256
#define QKVW 384
#define SCALE 0.08838834764831845f   // 1/sqrt(128)
#define QT 16
#define KT 64

typedef __attribute__((ext_vector_type(8))) short short8;
typedef __attribute__((ext_vector_type(4))) float floatx4;

// ---------------- reductions (256-thread block, 4 waves) ----------------
__device__ __forceinline__ float block_sum(float v, float* red) {
    #pragma unroll
    for (int o = 32; o > 0; o >>= 1) v += __shfl_down(v, o, 64);
    __syncthreads();
    int lane = threadIdx.x & 63, wv = threadIdx.x >> 6;
    if (lane == 0) red[wv] = v;
    __syncthreads();
    return red[0] + red[1] + red[2] + red[3];
}

__device__ __forceinline__ short8 pack8(float4 a, float4 b) {
    union { __hip_bfloat16 h[8]; short8 v; } o;
    o.h[0] = __float2bfloat16(a.x); o.h[1] = __float2bfloat16(a.y);
    o.h[2] = __float2bfloat16(a.z); o.h[3] = __float2bfloat16(a.w);
    o.h[4] = __float2bfloat16(b.x); o.h[5] = __float2bfloat16(b.y);
    o.h[6] = __float2bfloat16(b.z); o.h[7] = __float2bfloat16(b.w);
    return o.v;
}

// ---------------- weight prep (once per call) ----------------
__global__ void pack_wqkv(const float* __restrict__ Wq, const float* __restrict__ Wk,
                          const float* __restrict__ Wvd, __hip_bfloat16* __restrict__ dst) {
    size_t base = ((size_t)blockIdx.x * 256 + threadIdx.x) * 8;
    int k = (int)(base & 1023);
    int rh = (int)(base >> 10);
    int h = rh / QKVW;
    int row = rh - h * QKVW;
    const float* srcs[3] = {Wq, Wk, Wvd};
    const float* s = srcs[row >> 7] + (((size_t)h * DH + (row & 127)) << 10) + k;
    *(short8*)(dst + base) = pack8(*(const float4*)s, *(const float4*)(s + 4));
}

__global__ void pack_wvu(const float* __restrict__ Wvu, __hip_bfloat16* __restrict__ dst) {
    size_t base = ((size_t)blockIdx.x * 256 + threadIdx.x) * 8;
    *(short8*)(dst + base) = pack8(*(const float4*)(Wvu + base), *(const float4*)(Wvu + base + 4));
}

// ---------------- stage 0: e = x ----------------
__global__ void init_e(const float4* __restrict__ x, float4* __restrict__ e) {
    int i = blockIdx.x * 256 + threadIdx.x;
    e[i] = x[i];
}

// ---------------- per-head: ebf = bf16(e) ----------------
__global__ void cast_e(const float* __restrict__ e, __hip_bfloat16* __restrict__ out) {
    size_t base = ((size_t)blockIdx.x * 256 + threadIdx.x) * 8;
    *(short8*)(out + base) = pack8(*(const float4*)(e + base), *(const float4*)(e + base + 4));
}

// ---------------- MFMA GEMM: C[M][ldc] = A[M][K] @ B[N][K]^T (all bf16) ---
// 64x64 tile, BK=32, 4 waves, each wave 2x2 MFMA 16x16x32 tiles.
template<int K>
__global__ __launch_bounds__(256) void gemm_bf16(const __hip_bfloat16* __restrict__ A,
                                                 const __hip_bfloat16* __restrict__ B,
                                                 __hip_bfloat16* __restrict__ C,
                                                 int ldc) {
    constexpr int LDK = 40;  // 32 + 8 pad (80B rows: banks spread mod-4)
    const int c0 = blockIdx.x * 64, r0 = blockIdx.y * 64;
    const int tid = threadIdx.x;
    const int wave = tid >> 6, lane = tid & 63;
    const int wr = (wave >> 1) * 32, wc = (wave & 1) * 32;
    const int frow = lane & 15, kgrp = (lane >> 4) * 8;
    const int sr = tid >> 2, sk = (tid & 3) * 8;   // staging: row, k-offset

    __shared__ __hip_bfloat16 As[64 * LDK];
    __shared__ __hip_bfloat16 Bs[64 * LDK];

    floatx4 acc[2][2] = {};

    for (int k0 = 0; k0 < K; k0 += 32) {
        __syncthreads();
        *(short8*)(As + sr * LDK + sk) = *(const short8*)(A + (size_t)(r0 + sr) * K + k0 + sk);
        *(short8*)(Bs + sr * LDK + sk) = *(const short8*)(B + (size_t)(c0 + sr) * K + k0 + sk);
        __syncthreads();
        short8 a0 = *(const short8*)(As + (wr + frow) * LDK + kgrp);
        short8 a1 = *(const short8*)(As + (wr + 16 + frow) * LDK + kgrp);
        short8 b0 = *(const short8*)(Bs + (wc + frow) * LDK + kgrp);
        short8 b1 = *(const short8*)(Bs + (wc + 16 + frow) * LDK + kgrp);
        acc[0][0] = __builtin_amdgcn_mfma_f32_16x16x32_bf16(a0, b0, acc[0][0], 0, 0, 0);
        acc[0][1] = __builtin_amdgcn_mfma_f32_16x16x32_bf16(a0, b1, acc[0][1], 0, 0, 0);
        acc[1][0] = __builtin_amdgcn_mfma_f32_16x16x32_bf16(a1, b0, acc[1][0], 0, 0, 0);
        acc[1][1] = __builtin_amdgcn_mfma_f32_16x16x32_bf16(a1, b1, acc[1][1], 0, 0, 0);
    }

    #pragma unroll
    for (int i = 0; i < 2; i++)
        #pragma unroll
        for (int j = 0; j < 2; j++)
            #pragma unroll
            for (int r = 0; r < 4; r++) {
                int row = r0 + wr + i * 16 + (lane >> 4) * 4 + r;
                int col = c0 + wc + j * 16 + (lane & 15);
                C[(size_t)row * ldc + col] = __float2bfloat16(acc[i][j][r]);
            }
}

// ---------------- flash-style banded attention (bf16 in/out, fp32 math) ---
__global__ __launch_bounds__(256) void attn_tile(const __hip_bfloat16* __restrict__ qkv,
                                                 __hip_bfloat16* __restrict__ u) {
    const int q0 = blockIdx.x * QT;
    const int tid = threadIdx.x;
    const int ty = tid >> 4, tx = tid & 15;

    __shared__ float Qs[QT][DH];
    __shared__ float Ks[KT][DH + 4];
    __shared__ float Vs[KT][DH + 4];
    __shared__ float Ps[QT][KT + 1];

    {   // Q tile: 16x128 bf16 = 256 chunks of 8
        int r = tid >> 4, c8 = (tid & 15) * 8;
        union { short8 s; __hip_bfloat16 h[8]; } qv;
        qv.s = *(const short8*)(qkv + (size_t)(q0 + r) * QKVW + c8);
        #pragma unroll
        for (int i = 0; i < 8; i++) Qs[r][c8 + i] = __bfloat162float(qv.h[i]) * SCALE;
    }

    const int qg = q0 + ty;
    const int kstart = max(q0 - CWIN, 0);
    const int kend   = min(q0 + QT - 1 + CWIN + 1, NTOK);

    float mrow = -1e30f, lrow = 0.f;
    float O[8] = {};

    for (int kt = kstart; kt < kend; kt += KT) {
        __syncthreads();
        #pragma unroll
        for (int it = 0; it < 4; it++) {
            int idx = tid + 256 * it;
            int r = idx >> 4, c8 = (idx & 15) * 8;
            int t = kt + r;
            if (t < kend) {
                union { short8 s; __hip_bfloat16 h[8]; } kv, vv;
                kv.s = *(const short8*)(qkv + (size_t)t * QKVW + DH + c8);
                vv.s = *(const short8*)(qkv + (size_t)t * QKVW + 2 * DH + c8);
                #pragma unroll
                for (int i = 0; i < 8; i++) {
                    Ks[r][c8 + i] = __bfloat162float(kv.h[i]);
                    Vs[r][c8 + i] = __bfloat162float(vv.h[i]);
                }
            } else {
                #pragma unroll
                for (int i = 0; i < 8; i++) { Ks[r][c8 + i] = 0.f; Vs[r][c8 + i] = 0.f; }
            }
        }
        __syncthreads();

        float acc[4] = {0.f, 0.f, 0.f, 0.f};
        const float4* q4 = (const float4*)&Qs[ty][0];
        #pragma unroll 8
        for (int d4 = 0; d4 < DH / 4; d4++) {
            float4 qv = q4[d4];
            #pragma unroll
            for (int c = 0; c < 4; c++) {
                float4 kv = *(const float4*)&Ks[tx + 16 * c][d4 * 4];
                acc[c] += qv.x * kv.x + qv.y * kv.y + qv.z * kv.z + qv.w * kv.w;
            }
        }
        bool val[4];
        #pragma unroll
        for (int c = 0; c < 4; c++) {
            int t = kt + tx + 16 * c;
            val[c] = (t < kend) && (t >= qg - CWIN) && (t < qg + CWIN);
            Ps[ty][tx + 16 * c] = val[c] ? acc[c] : -1e30f;
        }
        __syncthreads();

        float tmax = -1e30f;
        #pragma unroll 8
        for (int k = 0; k < KT; k++) tmax = fmaxf(tmax, Ps[ty][k]);
        float mnew = fmaxf(mrow, tmax);
        float alpha = __expf(mrow - mnew);
        __syncthreads();

        #pragma unroll
        for (int c = 0; c < 4; c++)
            Ps[ty][tx + 16 * c] = val[c] ? __expf(acc[c] - mnew) : 0.f;
        __syncthreads();

        float psum = 0.f;
        #pragma unroll 8
        for (int k = 0; k < KT; k++) psum += Ps[ty][k];
        lrow = alpha * lrow + psum;
        mrow = mnew;
        #pragma unroll
        for (int i = 0; i < 8; i++) O[i] *= alpha;

        #pragma unroll 8
        for (int k = 0; k < KT; k++) {
            float p = Ps[ty][k];
            #pragma unroll
            for (int i = 0; i < 8; i++) O[i] += p * Vs[k][tx + 16 * i];
        }
    }

    float invl = 1.0f / lrow;
    #pragma unroll
    for (int i = 0; i < 8; i++)
        u[(size_t)qg * DH + tx + 16 * i] = __float2bfloat16(O[i] * invl);
}

// ---------------- residual + double-norm (delta in bf16) ------------------
__global__ __launch_bounds__(256) void norm_row(const __hip_bfloat16* __restrict__ delta,
                                                float* __restrict__ e) {
    const int j = blockIdx.x, tid = threadIdx.x;
    __shared__ float red[4];
    float4 eo = ((const float4*)e)[(size_t)j * 256 + tid];
    union { uint2 u2; __hip_bfloat16 h[4]; } db;
    db.u2 = *(const uint2*)(delta + (size_t)j * DEMB + tid * 4);
    float4 out = make_float4(eo.x + __bfloat162float(db.h[0]),
                             eo.y + __bfloat162float(db.h[1]),
                             eo.z + __bfloat162float(db.h[2]),
                             eo.w + __bfloat162float(db.h[3]));

    float m0 = block_sum(out.x + out.y + out.z + out.w, red) * (1.0f / DEMB);
    float inv_m0 = 1.0f / m0;
    out.x *= inv_m0; out.y *= inv_m0; out.z *= inv_m0; out.w *= inv_m0;

    float m = block_sum(out.x + out.y + out.z + out.w, red) * (1.0f / DEMB);

    float dx = out.x - m, dy = out.y - m, dz = out.z - m, dw = out.w - m;
    float var = block_sum(dx * dx + dy * dy + dz * dz + dw * dw, red)
              * (1.0f / (DEMB - 1));
    float inv_sd = rsqrtf(var);

    float4 res;
    res.x = eo.x + dx * inv_sd + m;
    res.y = eo.y + dy * inv_sd + m;
    res.z = eo.z + dz * inv_sd + m;
    res.w = eo.w + dw * inv_sd + m;
    ((float4*)e)[(size_t)j * 256 + tid] = res;
}

// ---------------- out = e / H ----------------
__global__ void final_scale(const float4* __restrict__ e, float4* __restrict__ out) {
    int i = blockIdx.x * 256 + threadIdx.x;
    float4 v = e[i];
    out[i] = make_float4(v.x * 0.125f, v.y * 0.125f, v.z * 0.125f, v.w * 0.125f);
}

extern "C" void kernel_launch(void* const* d_in, const int* in_sizes, int n_in,
                              void* d_out, int out_size, void* d_ws, size_t ws_size,
                              hipStream_t stream) {
    const float* x   = (const float*)d_in[0];
    const float* Wq  = (const float*)d_in[1];
    const float* Wk  = (const float*)d_in[2];
    const float* Wvd = (const float*)d_in[3];
    const float* Wvu = (const float*)d_in[4];
    float* out = (float*)d_out;

    char* ws = (char*)d_ws;
    float* e = (float*)ws;                                             // 16 MB
    __hip_bfloat16* ebf   = (__hip_bfloat16*)(ws + (16u << 20));       //  8 MB
    __hip_bfloat16* delta = ebf;                                       // alias (ebf dead by then)
    __hip_bfloat16* qkvb  = (__hip_bfloat16*)(ws + (24u << 20));       //  3 MB
    __hip_bfloat16* ub    = (__hip_bfloat16*)(ws + (27u << 20));       //  1 MB
    __hip_bfloat16* wqkvb = (__hip_bfloat16*)(ws + (28u << 20));       //  6 MB
    __hip_bfloat16* wvub  = (__hip_bfloat16*)(ws + (34u << 20));       //  2 MB  -> 36 MB total

    pack_wqkv<<<NH * QKVW * DEMB / 8 / 256, 256, 0, stream>>>(Wq, Wk, Wvd, wqkvb);
    pack_wvu<<<NH * DEMB * DH / 8 / 256, 256, 0, stream>>>(Wvu, wvub);
    init_e<<<NTOK * DEMB / 4 / 256, 256, 0, stream>>>((const float4*)x, (float4*)e);

    for (int h = 0; h < NH; h++) {
        cast_e<<<NTOK * DEMB / 8 / 256, 256, 0, stream>>>(e, ebf);
        gemm_bf16<DEMB><<<dim3(QKVW / 64, NTOK / 64), 256, 0, stream>>>(
            ebf, wqkvb + (size_t)h * QKVW * DEMB, qkvb, QKVW);
        attn_tile<<<NTOK / QT, 256, 0, stream>>>(qkvb, ub);
        gemm_bf16<DH><<<dim3(DEMB / 64, NTOK / 64), 256, 0, stream>>>(
            ub, wvub + (size_t)h * DEMB * DH, delta, DEMB);
        norm_row<<<NTOK, 256, 0, stream>>>(delta, e);
    }

    final_scale<<<NTOK * DEMB / 4 / 256, 256, 0, stream>>>((const float4*)e, (float4*)out);
}

// Round 5
// 487.887 us; speedup vs baseline: 17.3065x; 2.3087x over previous
//
#include <hip/hip_runtime.h>
#include <hip/hip_bf16.h>

#define NTOK 4096
#define DEMB 1024
#define NH   8
#define DH   128
#define CWIN 256
#define QKVW 384
#define SCALE 0.08838834764831845f   // 1/sqrt(128)
#define QT 16
#define KT 64

typedef __attribute__((ext_vector_type(8))) short short8;
typedef __attribute__((ext_vector_type(4))) float floatx4;

// ---------------- reductions (256-thread block, 4 waves) ----------------
__device__ __forceinline__ float block_sum(float v, float* red) {
    #pragma unroll
    for (int o = 32; o > 0; o >>= 1) v += __shfl_down(v, o, 64);
    __syncthreads();
    int lane = threadIdx.x & 63, wv = threadIdx.x >> 6;
    if (lane == 0) red[wv] = v;
    __syncthreads();
    return red[0] + red[1] + red[2] + red[3];
}

__device__ __forceinline__ short8 pack8(float4 a, float4 b) {
    union { __hip_bfloat16 h[8]; short8 v; } o;
    o.h[0] = __float2bfloat16(a.x); o.h[1] = __float2bfloat16(a.y);
    o.h[2] = __float2bfloat16(a.z); o.h[3] = __float2bfloat16(a.w);
    o.h[4] = __float2bfloat16(b.x); o.h[5] = __float2bfloat16(b.y);
    o.h[6] = __float2bfloat16(b.z); o.h[7] = __float2bfloat16(b.w);
    return o.v;
}

// ---------------- weight prep (once per call) ----------------
__global__ void pack_wqkv(const float* __restrict__ Wq, const float* __restrict__ Wk,
                          const float* __restrict__ Wvd, __hip_bfloat16* __restrict__ dst) {
    size_t base = ((size_t)blockIdx.x * 256 + threadIdx.x) * 8;
    int k = (int)(base & 1023);
    int rh = (int)(base >> 10);
    int h = rh / QKVW;
    int row = rh - h * QKVW;
    const float* srcs[3] = {Wq, Wk, Wvd};
    const float* s = srcs[row >> 7] + (((size_t)h * DH + (row & 127)) << 10) + k;
    *(short8*)(dst + base) = pack8(*(const float4*)s, *(const float4*)(s + 4));
}

__global__ void pack_wvu(const float* __restrict__ Wvu, __hip_bfloat16* __restrict__ dst) {
    size_t base = ((size_t)blockIdx.x * 256 + threadIdx.x) * 8;
    *(short8*)(dst + base) = pack8(*(const float4*)(Wvu + base), *(const float4*)(Wvu + base + 4));
}

// ---------------- stage 0: e = x (+ bf16 mirror) ----------------
__global__ void init_e(const float4* __restrict__ x, float4* __restrict__ e,
                       __hip_bfloat16* __restrict__ ebf) {
    int i = blockIdx.x * 256 + threadIdx.x;
    float4 v = x[i];
    e[i] = v;
    union { __hip_bfloat16 h[4]; uint2 u; } p;
    p.h[0] = __float2bfloat16(v.x); p.h[1] = __float2bfloat16(v.y);
    p.h[2] = __float2bfloat16(v.z); p.h[3] = __float2bfloat16(v.w);
    *(uint2*)(ebf + (size_t)i * 4) = p.u;
}

// ---------------- qkv GEMM: emits Q (scaled), K, V^T --------------------
// C[4096][384] = ebf @ Wqkv^T. 64x64 tile, BK=32, 4 waves, 2x2 MFMA each.
__global__ __launch_bounds__(256) void qkv_gemm_mfma(const __hip_bfloat16* __restrict__ A,
                                                     const __hip_bfloat16* __restrict__ B,
                                                     __hip_bfloat16* __restrict__ Qb,
                                                     __hip_bfloat16* __restrict__ Kb,
                                                     __hip_bfloat16* __restrict__ Vtb) {
    constexpr int K = DEMB;
    constexpr int LDK = 40;
    const int c0 = blockIdx.x * 64, r0 = blockIdx.y * 64;
    const int tid = threadIdx.x;
    const int wave = tid >> 6, lane = tid & 63;
    const int wr = (wave >> 1) * 32, wc = (wave & 1) * 32;
    const int frow = lane & 15, kgrp = (lane >> 4) * 8;
    const int quad = lane >> 4;
    const int sr = tid >> 2, sk = (tid & 3) * 8;

    __shared__ __hip_bfloat16 As[64 * LDK];
    __shared__ __hip_bfloat16 Bs[64 * LDK];

    floatx4 acc[2][2] = {};

    for (int k0 = 0; k0 < K; k0 += 32) {
        __syncthreads();
        *(short8*)(As + sr * LDK + sk) = *(const short8*)(A + (size_t)(r0 + sr) * K + k0 + sk);
        *(short8*)(Bs + sr * LDK + sk) = *(const short8*)(B + (size_t)(c0 + sr) * K + k0 + sk);
        __syncthreads();
        short8 a0 = *(const short8*)(As + (wr + frow) * LDK + kgrp);
        short8 a1 = *(const short8*)(As + (wr + 16 + frow) * LDK + kgrp);
        short8 b0 = *(const short8*)(Bs + (wc + frow) * LDK + kgrp);
        short8 b1 = *(const short8*)(Bs + (wc + 16 + frow) * LDK + kgrp);
        acc[0][0] = __builtin_amdgcn_mfma_f32_16x16x32_bf16(a0, b0, acc[0][0], 0, 0, 0);
        acc[0][1] = __builtin_amdgcn_mfma_f32_16x16x32_bf16(a0, b1, acc[0][1], 0, 0, 0);
        acc[1][0] = __builtin_amdgcn_mfma_f32_16x16x32_bf16(a1, b0, acc[1][0], 0, 0, 0);
        acc[1][1] = __builtin_amdgcn_mfma_f32_16x16x32_bf16(a1, b1, acc[1][1], 0, 0, 0);
    }

    #pragma unroll
    for (int i = 0; i < 2; i++)
        #pragma unroll
        for (int j = 0; j < 2; j++) {
            int col = c0 + wc + j * 16 + frow;
            int row0 = r0 + wr + i * 16 + quad * 4;
            if (col < DH) {            // Q, pre-scaled
                #pragma unroll
                for (int r = 0; r < 4; r++)
                    Qb[(size_t)(row0 + r) * DH + col] = __float2bfloat16(acc[i][j][r] * SCALE);
            } else if (col < 2 * DH) { // K
                #pragma unroll
                for (int r = 0; r < 4; r++)
                    Kb[(size_t)(row0 + r) * DH + col - DH] = __float2bfloat16(acc[i][j][r]);
            } else {                   // V, stored transposed: Vtb[d][token]
                union { __hip_bfloat16 h[4]; uint2 u; } p;
                #pragma unroll
                for (int r = 0; r < 4; r++) p.h[r] = __float2bfloat16(acc[i][j][r]);
                *(uint2*)(Vtb + (size_t)(col - 2 * DH) * NTOK + row0) = p.u;
            }
        }
}

// ---------------- MFMA flash attention (banded) ---------------------------
// grid 256 (16 queries each), 4 waves. QK^T, online softmax, PV all per-tile.
__global__ __launch_bounds__(256) void attn_mfma(const __hip_bfloat16* __restrict__ Qb,
                                                 const __hip_bfloat16* __restrict__ Kb,
                                                 const __hip_bfloat16* __restrict__ Vtb,
                                                 __hip_bfloat16* __restrict__ u) {
    const int q0 = blockIdx.x * QT;
    const int tid = threadIdx.x;
    const int wave = tid >> 6, lane = tid & 63;
    const int fr = lane & 15, kg = (lane >> 4) * 8;
    const int quad = lane >> 4;

    __shared__ __hip_bfloat16 Qs[QT][DH + 8];
    __shared__ __hip_bfloat16 Ks[KT][DH + 8];
    __shared__ __hip_bfloat16 Vts[DH][KT + 8];
    __shared__ float Pr[QT][KT + 4];
    __shared__ __hip_bfloat16 Pb[QT][KT + 8];
    __shared__ float alpha_s[QT];
    __shared__ float linv_s[QT];

    {   // stage Q: 16 rows x 16 chunks of 8 = 256 chunks
        int r = tid >> 4, c8 = (tid & 15) * 8;
        *(short8*)&Qs[r][c8] = *(const short8*)(Qb + (size_t)(q0 + r) * DH + c8);
    }
    __syncthreads();
    short8 af[4];                      // Q fragments are k-loop invariant
    #pragma unroll
    for (int kc = 0; kc < 4; kc++) af[kc] = *(const short8*)&Qs[fr][kc * 32 + kg];

    const int kstart = max(q0 - CWIN, 0);
    const int kend   = min(q0 + QT - 1 + CWIN + 1, NTOK);

    float mrow = -1e30f, lrow = 0.f;   // row = tid>>4 (softmax distribution)
    floatx4 Ofrag[2] = {};             // wave owns dims [32*wave, 32*wave+32)

    for (int kt = kstart; kt < kend; kt += KT) {
        __syncthreads();               // prior tile PV reads done
        if (kt + KT <= kend) {         // fast staging
            #pragma unroll
            for (int i = 0; i < 4; i++) {
                int idx = tid + 256 * i;
                int r = idx >> 4, c8 = (idx & 15) * 8;
                *(short8*)&Ks[r][c8] = *(const short8*)(Kb + (size_t)(kt + r) * DH + c8);
            }
            #pragma unroll
            for (int i = 0; i < 4; i++) {
                int idx = tid + 256 * i;
                int d = idx >> 3, c8 = (idx & 7) * 8;
                *(short8*)&Vts[d][c8] = *(const short8*)(Vtb + (size_t)d * NTOK + kt + c8);
            }
        } else {                       // boundary tile: zero-pad
            #pragma unroll
            for (int i = 0; i < 4; i++) {
                int idx = tid + 256 * i;
                int r = idx >> 4, c8 = (idx & 15) * 8;
                short8 z = {};
                *(short8*)&Ks[r][c8] = (kt + r < kend)
                    ? *(const short8*)(Kb + (size_t)(kt + r) * DH + c8) : z;
            }
            #pragma unroll
            for (int i = 0; i < 4; i++) {
                int idx = tid + 256 * i;
                int d = idx >> 3, c8 = (idx & 7) * 8;
                if (kt + c8 + 7 < kend) {
                    *(short8*)&Vts[d][c8] = *(const short8*)(Vtb + (size_t)d * NTOK + kt + c8);
                } else {
                    #pragma unroll
                    for (int t = 0; t < 8; t++)
                        Vts[d][c8 + t] = (kt + c8 + t < kend)
                            ? Vtb[(size_t)d * NTOK + kt + c8 + t] : __float2bfloat16(0.f);
                }
            }
        }
        __syncthreads();

        // ---- QK^T: wave computes S[16q][16k] for keys kt+16*wave..+16
        floatx4 s = {};
        #pragma unroll
        for (int kc = 0; kc < 4; kc++) {
            short8 bf = *(const short8*)&Ks[wave * 16 + fr][kc * 32 + kg];
            s = __builtin_amdgcn_mfma_f32_16x16x32_bf16(af[kc], bf, s, 0, 0, 0);
        }
        const int tcol = kt + wave * 16 + fr;
        #pragma unroll
        for (int r = 0; r < 4; r++) {
            int qg = q0 + quad * 4 + r;
            bool ok = (tcol < kend) && (tcol >= qg - CWIN) && (tcol < qg + CWIN);
            Pr[quad * 4 + r][wave * 16 + fr] = ok ? s[r] : -1e30f;
        }
        __syncthreads();

        // ---- online softmax: thread (r = tid>>4, c = tid&15) covers 4 cols
        {
            int r = tid >> 4, c = tid & 15;
            float v0 = Pr[r][c], v1 = Pr[r][c + 16], v2 = Pr[r][c + 32], v3 = Pr[r][c + 48];
            float tmax = fmaxf(fmaxf(v0, v1), fmaxf(v2, v3));
            #pragma unroll
            for (int m = 1; m <= 8; m <<= 1) tmax = fmaxf(tmax, __shfl_xor(tmax, m, 64));
            float mnew = fmaxf(mrow, tmax);
            float al = __expf(mrow - mnew);
            float p0 = __expf(v0 - mnew), p1 = __expf(v1 - mnew);
            float p2 = __expf(v2 - mnew), p3 = __expf(v3 - mnew);
            float ps = p0 + p1 + p2 + p3;
            #pragma unroll
            for (int m = 1; m <= 8; m <<= 1) ps += __shfl_xor(ps, m, 64);
            lrow = al * lrow + ps;
            mrow = mnew;
            Pb[r][c]      = __float2bfloat16(p0);
            Pb[r][c + 16] = __float2bfloat16(p1);
            Pb[r][c + 32] = __float2bfloat16(p2);
            Pb[r][c + 48] = __float2bfloat16(p3);
            if (c == 0) alpha_s[r] = al;
        }
        __syncthreads();

        // ---- PV: O[16][32w..] = alpha*O + P @ V
        {
            float a0 = alpha_s[quad * 4 + 0], a1 = alpha_s[quad * 4 + 1];
            float a2 = alpha_s[quad * 4 + 2], a3 = alpha_s[quad * 4 + 3];
            #pragma unroll
            for (int sx = 0; sx < 2; sx++) {
                Ofrag[sx][0] *= a0; Ofrag[sx][1] *= a1;
                Ofrag[sx][2] *= a2; Ofrag[sx][3] *= a3;
            }
            #pragma unroll
            for (int kc = 0; kc < 2; kc++) {
                short8 pf = *(const short8*)&Pb[fr][kc * 32 + kg];
                #pragma unroll
                for (int sx = 0; sx < 2; sx++) {
                    short8 vf = *(const short8*)&Vts[wave * 32 + sx * 16 + fr][kc * 32 + kg];
                    Ofrag[sx] = __builtin_amdgcn_mfma_f32_16x16x32_bf16(pf, vf, Ofrag[sx], 0, 0, 0);
                }
            }
        }
    }

    if ((tid & 15) == 0) linv_s[tid >> 4] = 1.0f / lrow;
    __syncthreads();
    #pragma unroll
    for (int sx = 0; sx < 2; sx++) {
        int col = wave * 32 + sx * 16 + fr;
        #pragma unroll
        for (int r = 0; r < 4; r++) {
            int row = quad * 4 + r;
            u[(size_t)(q0 + row) * DH + col] = __float2bfloat16(Ofrag[sx][r] * linv_s[row]);
        }
    }
}

// ---------------- delta GEMM: C[M][1024] = ub @ Wvu^T (bf16 MFMA) ---------
template<int K>
__global__ __launch_bounds__(256) void gemm_bf16(const __hip_bfloat16* __restrict__ A,
                                                 const __hip_bfloat16* __restrict__ B,
                                                 __hip_bfloat16* __restrict__ C,
                                                 int ldc) {
    constexpr int LDK = 40;
    const int c0 = blockIdx.x * 64, r0 = blockIdx.y * 64;
    const int tid = threadIdx.x;
    const int wave = tid >> 6, lane = tid & 63;
    const int wr = (wave >> 1) * 32, wc = (wave & 1) * 32;
    const int frow = lane & 15, kgrp = (lane >> 4) * 8;
    const int sr = tid >> 2, sk = (tid & 3) * 8;

    __shared__ __hip_bfloat16 As[64 * LDK];
    __shared__ __hip_bfloat16 Bs[64 * LDK];

    floatx4 acc[2][2] = {};

    for (int k0 = 0; k0 < K; k0 += 32) {
        __syncthreads();
        *(short8*)(As + sr * LDK + sk) = *(const short8*)(A + (size_t)(r0 + sr) * K + k0 + sk);
        *(short8*)(Bs + sr * LDK + sk) = *(const short8*)(B + (size_t)(c0 + sr) * K + k0 + sk);
        __syncthreads();
        short8 a0 = *(const short8*)(As + (wr + frow) * LDK + kgrp);
        short8 a1 = *(const short8*)(As + (wr + 16 + frow) * LDK + kgrp);
        short8 b0 = *(const short8*)(Bs + (wc + frow) * LDK + kgrp);
        short8 b1 = *(const short8*)(Bs + (wc + 16 + frow) * LDK + kgrp);
        acc[0][0] = __builtin_amdgcn_mfma_f32_16x16x32_bf16(a0, b0, acc[0][0], 0, 0, 0);
        acc[0][1] = __builtin_amdgcn_mfma_f32_16x16x32_bf16(a0, b1, acc[0][1], 0, 0, 0);
        acc[1][0] = __builtin_amdgcn_mfma_f32_16x16x32_bf16(a1, b0, acc[1][0], 0, 0, 0);
        acc[1][1] = __builtin_amdgcn_mfma_f32_16x16x32_bf16(a1, b1, acc[1][1], 0, 0, 0);
    }

    #pragma unroll
    for (int i = 0; i < 2; i++)
        #pragma unroll
        for (int j = 0; j < 2; j++)
            #pragma unroll
            for (int r = 0; r < 4; r++) {
                int row = r0 + wr + i * 16 + (lane >> 4) * 4 + r;
                int col = c0 + wc + j * 16 + (lane & 15);
                C[(size_t)row * ldc + col] = __float2bfloat16(acc[i][j][r]);
            }
}

// ---------------- residual + double-norm; writes e, ebf, (optional) out ---
__global__ __launch_bounds__(256) void norm_row(const __hip_bfloat16* __restrict__ delta,
                                                float* __restrict__ e,
                                                __hip_bfloat16* __restrict__ ebf,
                                                float4* __restrict__ out_final) {
    const int j = blockIdx.x, tid = threadIdx.x;
    __shared__ float red[4];
    float4 eo = ((const float4*)e)[(size_t)j * 256 + tid];
    union { uint2 u2; __hip_bfloat16 h[4]; } db;
    db.u2 = *(const uint2*)(delta + (size_t)j * DEMB + tid * 4);
    float4 out = make_float4(eo.x + __bfloat162float(db.h[0]),
                             eo.y + __bfloat162float(db.h[1]),
                             eo.z + __bfloat162float(db.h[2]),
                             eo.w + __bfloat162float(db.h[3]));

    float m0 = block_sum(out.x + out.y + out.z + out.w, red) * (1.0f / DEMB);
    float inv_m0 = 1.0f / m0;
    out.x *= inv_m0; out.y *= inv_m0; out.z *= inv_m0; out.w *= inv_m0;

    float m = block_sum(out.x + out.y + out.z + out.w, red) * (1.0f / DEMB);

    float dx = out.x - m, dy = out.y - m, dz = out.z - m, dw = out.w - m;
    float var = block_sum(dx * dx + dy * dy + dz * dz + dw * dw, red)
              * (1.0f / (DEMB - 1));
    float inv_sd = rsqrtf(var);

    float4 res;
    res.x = eo.x + dx * inv_sd + m;
    res.y = eo.y + dy * inv_sd + m;
    res.z = eo.z + dz * inv_sd + m;
    res.w = eo.w + dw * inv_sd + m;
    ((float4*)e)[(size_t)j * 256 + tid] = res;

    union { __hip_bfloat16 h[4]; uint2 u; } p;
    p.h[0] = __float2bfloat16(res.x); p.h[1] = __float2bfloat16(res.y);
    p.h[2] = __float2bfloat16(res.z); p.h[3] = __float2bfloat16(res.w);
    *(uint2*)(ebf + (size_t)j * DEMB + tid * 4) = p.u;

    if (out_final)
        out_final[(size_t)j * 256 + tid] =
            make_float4(res.x * 0.125f, res.y * 0.125f, res.z * 0.125f, res.w * 0.125f);
}

extern "C" void kernel_launch(void* const* d_in, const int* in_sizes, int n_in,
                              void* d_out, int out_size, void* d_ws, size_t ws_size,
                              hipStream_t stream) {
    const float* x   = (const float*)d_in[0];
    const float* Wq  = (const float*)d_in[1];
    const float* Wk  = (const float*)d_in[2];
    const float* Wvd = (const float*)d_in[3];
    const float* Wvu = (const float*)d_in[4];

    char* ws = (char*)d_ws;
    float* e = (float*)ws;                                              // 16 MB
    __hip_bfloat16* ebf   = (__hip_bfloat16*)(ws + (16u << 20));        //  8 MB (doubles as delta)
    __hip_bfloat16* Qb    = (__hip_bfloat16*)(ws + (24u << 20));        //  1 MB
    __hip_bfloat16* Kb    = (__hip_bfloat16*)(ws + (25u << 20));        //  1 MB
    __hip_bfloat16* Vtb   = (__hip_bfloat16*)(ws + (26u << 20));        //  1 MB
    __hip_bfloat16* ub    = (__hip_bfloat16*)(ws + (27u << 20));        //  1 MB
    __hip_bfloat16* wqkvb = (__hip_bfloat16*)(ws + (28u << 20));        //  6 MB
    __hip_bfloat16* wvub  = (__hip_bfloat16*)(ws + (34u << 20));        //  2 MB  -> 36 MB

    pack_wqkv<<<NH * QKVW * DEMB / 8 / 256, 256, 0, stream>>>(Wq, Wk, Wvd, wqkvb);
    pack_wvu<<<NH * DEMB * DH / 8 / 256, 256, 0, stream>>>(Wvu, wvub);
    init_e<<<NTOK * DEMB / 4 / 256, 256, 0, stream>>>((const float4*)x, (float4*)e, ebf);

    for (int h = 0; h < NH; h++) {
        qkv_gemm_mfma<<<dim3(QKVW / 64, NTOK / 64), 256, 0, stream>>>(
            ebf, wqkvb + (size_t)h * QKVW * DEMB, Qb, Kb, Vtb);
        attn_mfma<<<NTOK / QT, 256, 0, stream>>>(Qb, Kb, Vtb, ub);
        gemm_bf16<DH><<<dim3(DEMB / 64, NTOK / 64), 256, 0, stream>>>(
            ub, wvub + (size_t)h * DEMB * DH, ebf, DEMB);
        norm_row<<<NTOK, 256, 0, stream>>>(ebf, e, ebf,
            (h == NH - 1) ? (float4*)d_out : nullptr);
    }
}

// Round 6
// 484.523 us; speedup vs baseline: 17.4266x; 1.0069x over previous
//
#include <hip/hip_runtime.h>
#include <hip/hip_bf16.h>

#define NTOK 4096
#define DEMB 1024
#define NH   8
#define DH   128
#define CWIN 256
#define QKVW 384
#define SCALE 0.08838834764831845f   // 1/sqrt(128)
#define QT 16
#define KT2 128

typedef __attribute__((ext_vector_type(8))) short short8;
typedef __attribute__((ext_vector_type(4))) float floatx4;

__device__ __forceinline__ short8 pack8(float4 a, float4 b) {
    union { __hip_bfloat16 h[8]; short8 v; } o;
    o.h[0] = __float2bfloat16(a.x); o.h[1] = __float2bfloat16(a.y);
    o.h[2] = __float2bfloat16(a.z); o.h[3] = __float2bfloat16(a.w);
    o.h[4] = __float2bfloat16(b.x); o.h[5] = __float2bfloat16(b.y);
    o.h[6] = __float2bfloat16(b.z); o.h[7] = __float2bfloat16(b.w);
    return o.v;
}

// ---------------- weight prep (once per call) ----------------
__global__ void pack_wqkv(const float* __restrict__ Wq, const float* __restrict__ Wk,
                          const float* __restrict__ Wvd, __hip_bfloat16* __restrict__ dst) {
    size_t base = ((size_t)blockIdx.x * 256 + threadIdx.x) * 8;
    int k = (int)(base & 1023);
    int rh = (int)(base >> 10);
    int h = rh / QKVW;
    int row = rh - h * QKVW;
    const float* srcs[3] = {Wq, Wk, Wvd};
    const float* s = srcs[row >> 7] + (((size_t)h * DH + (row & 127)) << 10) + k;
    *(short8*)(dst + base) = pack8(*(const float4*)s, *(const float4*)(s + 4));
}

__global__ void pack_wvu(const float* __restrict__ Wvu, __hip_bfloat16* __restrict__ dst) {
    size_t base = ((size_t)blockIdx.x * 256 + threadIdx.x) * 8;
    *(short8*)(dst + base) = pack8(*(const float4*)(Wvu + base), *(const float4*)(Wvu + base + 4));
}

// ---------------- stage 0: e = x (+ bf16 mirror) ----------------
__global__ void init_e(const float4* __restrict__ x, float4* __restrict__ e,
                       __hip_bfloat16* __restrict__ ebf) {
    int i = blockIdx.x * 256 + threadIdx.x;
    float4 v = x[i];
    e[i] = v;
    union { __hip_bfloat16 h[4]; uint2 u; } p;
    p.h[0] = __float2bfloat16(v.x); p.h[1] = __float2bfloat16(v.y);
    p.h[2] = __float2bfloat16(v.z); p.h[3] = __float2bfloat16(v.w);
    *(uint2*)(ebf + (size_t)i * 4) = p.u;
}

// ---------------- qkv GEMM: emits Q (scaled), K, V^T --------------------
__global__ __launch_bounds__(256) void qkv_gemm_mfma(const __hip_bfloat16* __restrict__ A,
                                                     const __hip_bfloat16* __restrict__ B,
                                                     __hip_bfloat16* __restrict__ Qb,
                                                     __hip_bfloat16* __restrict__ Kb,
                                                     __hip_bfloat16* __restrict__ Vtb) {
    constexpr int K = DEMB;
    constexpr int LDK = 40;
    const int c0 = blockIdx.x * 64, r0 = blockIdx.y * 64;
    const int tid = threadIdx.x;
    const int wave = tid >> 6, lane = tid & 63;
    const int wr = (wave >> 1) * 32, wc = (wave & 1) * 32;
    const int frow = lane & 15, kgrp = (lane >> 4) * 8;
    const int quad = lane >> 4;
    const int sr = tid >> 2, sk = (tid & 3) * 8;

    __shared__ __hip_bfloat16 As[64 * LDK];
    __shared__ __hip_bfloat16 Bs[64 * LDK];

    floatx4 acc[2][2] = {};

    for (int k0 = 0; k0 < K; k0 += 32) {
        __syncthreads();
        *(short8*)(As + sr * LDK + sk) = *(const short8*)(A + (size_t)(r0 + sr) * K + k0 + sk);
        *(short8*)(Bs + sr * LDK + sk) = *(const short8*)(B + (size_t)(c0 + sr) * K + k0 + sk);
        __syncthreads();
        short8 a0 = *(const short8*)(As + (wr + frow) * LDK + kgrp);
        short8 a1 = *(const short8*)(As + (wr + 16 + frow) * LDK + kgrp);
        short8 b0 = *(const short8*)(Bs + (wc + frow) * LDK + kgrp);
        short8 b1 = *(const short8*)(Bs + (wc + 16 + frow) * LDK + kgrp);
        acc[0][0] = __builtin_amdgcn_mfma_f32_16x16x32_bf16(a0, b0, acc[0][0], 0, 0, 0);
        acc[0][1] = __builtin_amdgcn_mfma_f32_16x16x32_bf16(a0, b1, acc[0][1], 0, 0, 0);
        acc[1][0] = __builtin_amdgcn_mfma_f32_16x16x32_bf16(a1, b0, acc[1][0], 0, 0, 0);
        acc[1][1] = __builtin_amdgcn_mfma_f32_16x16x32_bf16(a1, b1, acc[1][1], 0, 0, 0);
    }

    #pragma unroll
    for (int i = 0; i < 2; i++)
        #pragma unroll
        for (int j = 0; j < 2; j++) {
            int col = c0 + wc + j * 16 + frow;
            int row0 = r0 + wr + i * 16 + quad * 4;
            if (col < DH) {            // Q, pre-scaled
                #pragma unroll
                for (int r = 0; r < 4; r++)
                    Qb[(size_t)(row0 + r) * DH + col] = __float2bfloat16(acc[i][j][r] * SCALE);
            } else if (col < 2 * DH) { // K
                #pragma unroll
                for (int r = 0; r < 4; r++)
                    Kb[(size_t)(row0 + r) * DH + col - DH] = __float2bfloat16(acc[i][j][r]);
            } else {                   // V, stored transposed: Vtb[d][token]
                union { __hip_bfloat16 h[4]; uint2 u; } p;
                #pragma unroll
                for (int r = 0; r < 4; r++) p.h[r] = __float2bfloat16(acc[i][j][r]);
                *(uint2*)(Vtb + (size_t)(col - 2 * DH) * NTOK + row0) = p.u;
            }
        }
}

// ---------------- mega kernel: flash attn + out-proj + residual/norm ------
// grid 256 (16 queries/block), 256 threads (4 waves).
__global__ __launch_bounds__(256) void attn_mega(const __hip_bfloat16* __restrict__ Qb,
                                                 const __hip_bfloat16* __restrict__ Kb,
                                                 const __hip_bfloat16* __restrict__ Vtb,
                                                 const __hip_bfloat16* __restrict__ Wvu, // [1024][128] this head
                                                 float* __restrict__ e,
                                                 __hip_bfloat16* __restrict__ ebf,
                                                 float4* __restrict__ out_final) {
    const int q0 = blockIdx.x * QT;
    const int tid = threadIdx.x;
    const int wave = tid >> 6, lane = tid & 63;
    const int fr = lane & 15, kg = (lane >> 4) * 8;
    const int quad = lane >> 4;

    __shared__ alignas(16) __hip_bfloat16 Qs[QT][DH + 8];      // later: Os (u rows, A-layout)
    __shared__ alignas(16) __hip_bfloat16 KV[2 * KT2][DH + 8]; // Ks | Vts; later: OutP fp32[16][1028]
    __shared__ alignas(16) float Pr[QT][KT2 + 4];
    __shared__ alignas(16) __hip_bfloat16 Pb[QT][KT2 + 8];
    __shared__ float alpha_s[QT];
    __shared__ float linv_s[QT];

    {   // stage Q
        int r = tid >> 4, c8 = (tid & 15) * 8;
        *(short8*)&Qs[r][c8] = *(const short8*)(Qb + (size_t)(q0 + r) * DH + c8);
    }
    __syncthreads();
    short8 af[4];
    #pragma unroll
    for (int kc = 0; kc < 4; kc++) af[kc] = *(const short8*)&Qs[fr][kc * 32 + kg];

    const int kstart = max(q0 - CWIN, 0);
    const int kend   = min(q0 + QT - 1 + CWIN + 1, NTOK);

    float mrow = -1e30f, lrow = 0.f;   // softmax state for row (tid>>4)
    floatx4 Ofrag[2] = {};             // wave owns dims [32*wave, 32*wave+32)

    // ================= flash loop, KT2 = 128 =================
    for (int kt = kstart; kt < kend; kt += KT2) {
        __syncthreads();
        if (kt + KT2 <= kend) {
            #pragma unroll
            for (int i = 0; i < 8; i++) {
                int idx = tid + 256 * i;
                int r = idx >> 4, c8 = (idx & 15) * 8;
                *(short8*)&KV[r][c8] = *(const short8*)(Kb + (size_t)(kt + r) * DH + c8);
            }
            #pragma unroll
            for (int i = 0; i < 8; i++) {
                int idx = tid + 256 * i;
                int d = idx >> 4, c8 = (idx & 15) * 8;
                *(short8*)&KV[KT2 + d][c8] = *(const short8*)(Vtb + (size_t)d * NTOK + kt + c8);
            }
        } else {
            #pragma unroll
            for (int i = 0; i < 8; i++) {
                int idx = tid + 256 * i;
                int r = idx >> 4, c8 = (idx & 15) * 8;
                short8 z = {};
                *(short8*)&KV[r][c8] = (kt + r < kend)
                    ? *(const short8*)(Kb + (size_t)(kt + r) * DH + c8) : z;
            }
            #pragma unroll
            for (int i = 0; i < 8; i++) {
                int idx = tid + 256 * i;
                int d = idx >> 4, c8 = (idx & 15) * 8;
                if (kt + c8 + 7 < kend) {
                    *(short8*)&KV[KT2 + d][c8] = *(const short8*)(Vtb + (size_t)d * NTOK + kt + c8);
                } else {
                    #pragma unroll
                    for (int t = 0; t < 8; t++)
                        KV[KT2 + d][c8 + t] = (kt + c8 + t < kend)
                            ? Vtb[(size_t)d * NTOK + kt + c8 + t] : __float2bfloat16(0.f);
                }
            }
        }
        __syncthreads();

        // ---- QK^T: wave covers keys [kt+32w, kt+32w+32) as 2 subtiles
        floatx4 s[2] = {};
        #pragma unroll
        for (int sx = 0; sx < 2; sx++)
            #pragma unroll
            for (int kc = 0; kc < 4; kc++) {
                short8 bf = *(const short8*)&KV[wave * 32 + sx * 16 + fr][kc * 32 + kg];
                s[sx] = __builtin_amdgcn_mfma_f32_16x16x32_bf16(af[kc], bf, s[sx], 0, 0, 0);
            }
        #pragma unroll
        for (int sx = 0; sx < 2; sx++) {
            int tcol = kt + wave * 32 + sx * 16 + fr;
            #pragma unroll
            for (int r = 0; r < 4; r++) {
                int qg = q0 + quad * 4 + r;
                bool ok = (tcol < kend) && (tcol >= qg - CWIN) && (tcol < qg + CWIN);
                Pr[quad * 4 + r][wave * 32 + sx * 16 + fr] = ok ? s[sx][r] : -1e30f;
            }
        }
        __syncthreads();

        // ---- online softmax: thread (r=tid>>4, c=tid&15) covers 8 cols
        {
            int r = tid >> 4, c = tid & 15;
            float v[8]; float tmax = -1e30f;
            #pragma unroll
            for (int i = 0; i < 8; i++) { v[i] = Pr[r][c + 16 * i]; tmax = fmaxf(tmax, v[i]); }
            #pragma unroll
            for (int m = 1; m <= 8; m <<= 1) tmax = fmaxf(tmax, __shfl_xor(tmax, m, 64));
            float mnew = fmaxf(mrow, tmax);
            float al = __expf(mrow - mnew);
            float ps = 0.f;
            #pragma unroll
            for (int i = 0; i < 8; i++) {
                float p = __expf(v[i] - mnew);
                Pb[r][c + 16 * i] = __float2bfloat16(p);
                ps += p;
            }
            #pragma unroll
            for (int m = 1; m <= 8; m <<= 1) ps += __shfl_xor(ps, m, 64);
            lrow = al * lrow + ps;
            mrow = mnew;
            if (c == 0) alpha_s[r] = al;
        }
        __syncthreads();

        // ---- PV: O[16][32w..] = alpha*O + P @ V (K = 128 this tile)
        {
            float a0 = alpha_s[quad * 4 + 0], a1 = alpha_s[quad * 4 + 1];
            float a2 = alpha_s[quad * 4 + 2], a3 = alpha_s[quad * 4 + 3];
            #pragma unroll
            for (int sx = 0; sx < 2; sx++) {
                Ofrag[sx][0] *= a0; Ofrag[sx][1] *= a1;
                Ofrag[sx][2] *= a2; Ofrag[sx][3] *= a3;
            }
            #pragma unroll
            for (int kc = 0; kc < 4; kc++) {
                short8 pf = *(const short8*)&Pb[fr][kc * 32 + kg];
                #pragma unroll
                for (int sx = 0; sx < 2; sx++) {
                    short8 vf = *(const short8*)&KV[KT2 + wave * 32 + sx * 16 + fr][kc * 32 + kg];
                    Ofrag[sx] = __builtin_amdgcn_mfma_f32_16x16x32_bf16(pf, vf, Ofrag[sx], 0, 0, 0);
                }
            }
        }
    }

    // ================= u rows -> LDS (A-layout), bf16 =================
    if ((tid & 15) == 0) linv_s[tid >> 4] = 1.0f / lrow;
    __syncthreads();
    #pragma unroll
    for (int sx = 0; sx < 2; sx++) {
        int col = wave * 32 + sx * 16 + fr;
        #pragma unroll
        for (int r = 0; r < 4; r++) {
            int row = quad * 4 + r;
            Qs[row][col] = __float2bfloat16(Ofrag[sx][r] * linv_s[row]);
        }
    }
    __syncthreads();   // Os complete; Ks/Vts dead from here

    // ================= out-proj: delta[16][1024] = u @ Wvu^T ===========
    float* OutP = (float*)&KV[0][0];   // [16][1028] fp32 overlay (65792 B <= 69632 B)

    // stage e rows into OutP (out_pre accumulates e + delta)
    #pragma unroll
    for (int i = 0; i < 16; i++)
        *(float4*)(OutP + i * 1028 + tid * 4) =
            *(const float4*)(e + (size_t)(q0 + i) * DEMB + tid * 4);

    short8 af2[4];
    #pragma unroll
    for (int kc = 0; kc < 4; kc++) af2[kc] = *(const short8*)&Qs[fr][kc * 32 + kg];

    floatx4 accd[16] = {};             // wave's 256 output cols, 16 tiles
    #pragma unroll
    for (int n0 = 0; n0 < 16; n0++) {
        const __hip_bfloat16* wrow = Wvu + ((size_t)(wave * 256 + n0 * 16 + fr) << 7);
        #pragma unroll
        for (int kc = 0; kc < 4; kc++) {
            short8 bf = *(const short8*)(wrow + kc * 32 + kg);
            accd[n0] = __builtin_amdgcn_mfma_f32_16x16x32_bf16(af2[kc], bf, accd[n0], 0, 0, 0);
        }
    }
    __syncthreads();   // e staged by all threads

    #pragma unroll
    for (int n0 = 0; n0 < 16; n0++) {
        int colb = wave * 256 + n0 * 16 + fr;
        #pragma unroll
        for (int r = 0; r < 4; r++)
            OutP[(quad * 4 + r) * 1028 + colb] += accd[n0][r];
    }
    __syncthreads();

    // ================= residual + double-norm =================
    {
        const int r = tid >> 4, c = tid & 15;
        float s0 = 0.f;
        #pragma unroll
        for (int i = 0; i < 64; i++) s0 += OutP[r * 1028 + c + 16 * i];
        #pragma unroll
        for (int m = 1; m <= 8; m <<= 1) s0 += __shfl_xor(s0, m, 64);
        float m0 = s0 * (1.0f / DEMB);
        float inv_m0 = 1.0f / m0;
        float m = m0 * inv_m0;         // == mean(out/m0) to ~1e-7

        float vs = 0.f;
        #pragma unroll
        for (int i = 0; i < 64; i++) {
            float t = OutP[r * 1028 + c + 16 * i] * inv_m0 - m;
            vs += t * t;
        }
        #pragma unroll
        for (int mm = 1; mm <= 8; mm <<= 1) vs += __shfl_xor(vs, mm, 64);
        float inv_sd = rsqrtf(vs * (1.0f / (DEMB - 1)));

        const size_t rowbase = (size_t)(q0 + r) * DEMB;
        #pragma unroll
        for (int i = 0; i < 16; i++) {
            int c4 = c + 16 * i;
            float4 v4 = *(const float4*)(OutP + r * 1028 + 4 * c4);
            float4 eo = *(const float4*)(e + rowbase + 4 * c4);
            float ox = v4.x * inv_m0, oy = v4.y * inv_m0;
            float oz = v4.z * inv_m0, ow = v4.w * inv_m0;
            float4 res;
            res.x = eo.x + (ox - m) * inv_sd + m;
            res.y = eo.y + (oy - m) * inv_sd + m;
            res.z = eo.z + (oz - m) * inv_sd + m;
            res.w = eo.w + (ow - m) * inv_sd + m;
            *(float4*)(e + rowbase + 4 * c4) = res;
            union { __hip_bfloat16 h[4]; uint2 u; } p;
            p.h[0] = __float2bfloat16(res.x); p.h[1] = __float2bfloat16(res.y);
            p.h[2] = __float2bfloat16(res.z); p.h[3] = __float2bfloat16(res.w);
            *(uint2*)(ebf + rowbase + 4 * c4) = p.u;
            if (out_final)
                out_final[(rowbase >> 2) + c4] = make_float4(res.x * 0.125f, res.y * 0.125f,
                                                            res.z * 0.125f, res.w * 0.125f);
        }
    }
}

extern "C" void kernel_launch(void* const* d_in, const int* in_sizes, int n_in,
                              void* d_out, int out_size, void* d_ws, size_t ws_size,
                              hipStream_t stream) {
    const float* x   = (const float*)d_in[0];
    const float* Wq  = (const float*)d_in[1];
    const float* Wk  = (const float*)d_in[2];
    const float* Wvd = (const float*)d_in[3];
    const float* Wvu = (const float*)d_in[4];

    char* ws = (char*)d_ws;
    float* e = (float*)ws;                                              // 16 MB
    __hip_bfloat16* ebf   = (__hip_bfloat16*)(ws + (16u << 20));        //  8 MB
    __hip_bfloat16* Qb    = (__hip_bfloat16*)(ws + (24u << 20));        //  1 MB
    __hip_bfloat16* Kb    = (__hip_bfloat16*)(ws + (25u << 20));        //  1 MB
    __hip_bfloat16* Vtb   = (__hip_bfloat16*)(ws + (26u << 20));        //  1 MB
    __hip_bfloat16* wqkvb = (__hip_bfloat16*)(ws + (28u << 20));        //  6 MB
    __hip_bfloat16* wvub  = (__hip_bfloat16*)(ws + (34u << 20));        //  2 MB  -> 36 MB

    pack_wqkv<<<NH * QKVW * DEMB / 8 / 256, 256, 0, stream>>>(Wq, Wk, Wvd, wqkvb);
    pack_wvu<<<NH * DEMB * DH / 8 / 256, 256, 0, stream>>>(Wvu, wvub);
    init_e<<<NTOK * DEMB / 4 / 256, 256, 0, stream>>>((const float4*)x, (float4*)e, ebf);

    for (int h = 0; h < NH; h++) {
        qkv_gemm_mfma<<<dim3(QKVW / 64, NTOK / 64), 256, 0, stream>>>(
            ebf, wqkvb + (size_t)h * QKVW * DEMB, Qb, Kb, Vtb);
        attn_mega<<<NTOK / QT, 256, 0, stream>>>(
            Qb, Kb, Vtb, wvub + (size_t)h * DEMB * DH, e, ebf,
            (h == NH - 1) ? (float4*)d_out : nullptr);
    }
}

// Round 7
// 479.430 us; speedup vs baseline: 17.6118x; 1.0106x over previous
//
#include <hip/hip_runtime.h>
#include <hip/hip_bf16.h>

#define NTOK 4096
#define DEMB 1024
#define NH   8
#define DH   128
#define CWIN 256
#define QKVW 384
#define SCALE 0.08838834764831845f   // 1/sqrt(128)
#define QT 16
#define NCH 34                        // 16-key chunks covering the 527-wide band

typedef __attribute__((ext_vector_type(8))) short short8;
typedef __attribute__((ext_vector_type(4))) float floatx4;

__device__ __forceinline__ short8 pack8(float4 a, float4 b) {
    union { __hip_bfloat16 h[8]; short8 v; } o;
    o.h[0] = __float2bfloat16(a.x); o.h[1] = __float2bfloat16(a.y);
    o.h[2] = __float2bfloat16(a.z); o.h[3] = __float2bfloat16(a.w);
    o.h[4] = __float2bfloat16(b.x); o.h[5] = __float2bfloat16(b.y);
    o.h[6] = __float2bfloat16(b.z); o.h[7] = __float2bfloat16(b.w);
    return o.v;
}

// ---------------- weight prep (once per call) ----------------
__global__ void pack_wqkv(const float* __restrict__ Wq, const float* __restrict__ Wk,
                          const float* __restrict__ Wvd, __hip_bfloat16* __restrict__ dst) {
    size_t base = ((size_t)blockIdx.x * 256 + threadIdx.x) * 8;
    int k = (int)(base & 1023);
    int rh = (int)(base >> 10);
    int h = rh / QKVW;
    int row = rh - h * QKVW;
    const float* srcs[3] = {Wq, Wk, Wvd};
    const float* s = srcs[row >> 7] + (((size_t)h * DH + (row & 127)) << 10) + k;
    *(short8*)(dst + base) = pack8(*(const float4*)s, *(const float4*)(s + 4));
}

__global__ void pack_wvu(const float* __restrict__ Wvu, __hip_bfloat16* __restrict__ dst) {
    size_t base = ((size_t)blockIdx.x * 256 + threadIdx.x) * 8;
    *(short8*)(dst + base) = pack8(*(const float4*)(Wvu + base), *(const float4*)(Wvu + base + 4));
}

// ---------------- stage 0: e = x (+ bf16 mirror) ----------------
__global__ void init_e(const float4* __restrict__ x, float4* __restrict__ e,
                       __hip_bfloat16* __restrict__ ebf) {
    int i = blockIdx.x * 256 + threadIdx.x;
    float4 v = x[i];
    e[i] = v;
    union { __hip_bfloat16 h[4]; uint2 u; } p;
    p.h[0] = __float2bfloat16(v.x); p.h[1] = __float2bfloat16(v.y);
    p.h[2] = __float2bfloat16(v.z); p.h[3] = __float2bfloat16(v.w);
    *(uint2*)(ebf + (size_t)i * 4) = p.u;
}

// ---------------- qkv GEMM: emits Q (scaled), K, V^T --------------------
__global__ __launch_bounds__(256) void qkv_gemm_mfma(const __hip_bfloat16* __restrict__ A,
                                                     const __hip_bfloat16* __restrict__ B,
                                                     __hip_bfloat16* __restrict__ Qb,
                                                     __hip_bfloat16* __restrict__ Kb,
                                                     __hip_bfloat16* __restrict__ Vtb) {
    constexpr int K = DEMB;
    constexpr int LDK = 40;
    const int c0 = blockIdx.x * 64, r0 = blockIdx.y * 64;
    const int tid = threadIdx.x;
    const int wave = tid >> 6, lane = tid & 63;
    const int wr = (wave >> 1) * 32, wc = (wave & 1) * 32;
    const int frow = lane & 15, kgrp = (lane >> 4) * 8;
    const int quad = lane >> 4;
    const int sr = tid >> 2, sk = (tid & 3) * 8;

    __shared__ __hip_bfloat16 As[64 * LDK];
    __shared__ __hip_bfloat16 Bs[64 * LDK];

    floatx4 acc[2][2] = {};

    for (int k0 = 0; k0 < K; k0 += 32) {
        __syncthreads();
        *(short8*)(As + sr * LDK + sk) = *(const short8*)(A + (size_t)(r0 + sr) * K + k0 + sk);
        *(short8*)(Bs + sr * LDK + sk) = *(const short8*)(B + (size_t)(c0 + sr) * K + k0 + sk);
        __syncthreads();
        short8 a0 = *(const short8*)(As + (wr + frow) * LDK + kgrp);
        short8 a1 = *(const short8*)(As + (wr + 16 + frow) * LDK + kgrp);
        short8 b0 = *(const short8*)(Bs + (wc + frow) * LDK + kgrp);
        short8 b1 = *(const short8*)(Bs + (wc + 16 + frow) * LDK + kgrp);
        acc[0][0] = __builtin_amdgcn_mfma_f32_16x16x32_bf16(a0, b0, acc[0][0], 0, 0, 0);
        acc[0][1] = __builtin_amdgcn_mfma_f32_16x16x32_bf16(a0, b1, acc[0][1], 0, 0, 0);
        acc[1][0] = __builtin_amdgcn_mfma_f32_16x16x32_bf16(a1, b0, acc[1][0], 0, 0, 0);
        acc[1][1] = __builtin_amdgcn_mfma_f32_16x16x32_bf16(a1, b1, acc[1][1], 0, 0, 0);
    }

    #pragma unroll
    for (int i = 0; i < 2; i++)
        #pragma unroll
        for (int j = 0; j < 2; j++) {
            int col = c0 + wc + j * 16 + frow;
            int row0 = r0 + wr + i * 16 + quad * 4;
            if (col < DH) {            // Q, pre-scaled
                #pragma unroll
                for (int r = 0; r < 4; r++)
                    Qb[(size_t)(row0 + r) * DH + col] = __float2bfloat16(acc[i][j][r] * SCALE);
            } else if (col < 2 * DH) { // K
                #pragma unroll
                for (int r = 0; r < 4; r++)
                    Kb[(size_t)(row0 + r) * DH + col - DH] = __float2bfloat16(acc[i][j][r]);
            } else {                   // V, stored transposed: Vtb[d][token]
                union { __hip_bfloat16 h[4]; uint2 u; } p;
                #pragma unroll
                for (int r = 0; r < 4; r++) p.h[r] = __float2bfloat16(acc[i][j][r]);
                *(uint2*)(Vtb + (size_t)(col - 2 * DH) * NTOK + row0) = p.u;
            }
        }
}

// ---------------- mega kernel v2: 512 threads, registers > LDS ------------
// grid 256 (16 queries/block), 8 waves. No K/V LDS staging (no cross-wave
// sharing exists); single-pass softmax over the whole <=527-key band.
// OOB fragment reads (band edges) land in adjacent ws buffers: finite bf16
// (poison 0xAAAA is finite), multiplied by p=0.
__global__ __launch_bounds__(512) void attn_mega(const __hip_bfloat16* __restrict__ Qb,
                                                 const __hip_bfloat16* __restrict__ Kb,
                                                 const __hip_bfloat16* __restrict__ Vtb,
                                                 const __hip_bfloat16* __restrict__ Wvu,
                                                 float* __restrict__ e,
                                                 __hip_bfloat16* __restrict__ ebf,
                                                 float* __restrict__ out_final) {
    const int q0 = blockIdx.x * QT;
    const int tid = threadIdx.x;
    const int wave = tid >> 6, lane = tid & 63;
    const int fr = lane & 15, kg = (lane >> 4) * 8;
    const int quad = lane >> 4;

    __shared__ alignas(16) __hip_bfloat16 Qs[QT][DH + 8];    // later: u rows
    __shared__ alignas(16) __hip_bfloat16 Pb[QT][NCH * 16 + 8];
    __shared__ float statsA[QT][8];
    __shared__ float statsB[QT][8];

    if (tid < 256) {   // stage Q (16x128 bf16)
        int r = tid >> 4, c8 = (tid & 15) * 8;
        *(short8*)&Qs[r][c8] = *(const short8*)(Qb + (size_t)(q0 + r) * DH + c8);
    }
    __syncthreads();
    short8 af[4];
    #pragma unroll
    for (int kc = 0; kc < 4; kc++) af[kc] = *(const short8*)&Qs[fr][kc * 32 + kg];

    const int kstart = max(q0 - CWIN, 0);
    const int kend   = min(q0 + QT - 1 + CWIN + 1, NTOK);
    const int nch = (wave < 2) ? 5 : 4;   // chunks ch = wave + 8t, ch < 34

    // ---- scores: each wave's chunks, K-fragments straight from L2 --------
    floatx4 sreg[5];
    #pragma unroll
    for (int t = 0; t < 5; t++) {
        if (t >= nch) break;
        int ch = wave + 8 * t;
        const __hip_bfloat16* krow = Kb + (size_t)(kstart + ch * 16 + fr) * DH;
        floatx4 s = {};
        #pragma unroll
        for (int kc = 0; kc < 4; kc++)
            s = __builtin_amdgcn_mfma_f32_16x16x32_bf16(af[kc],
                    *(const short8*)(krow + kc * 32 + kg), s, 0, 0, 0);
        sreg[t] = s;
    }

    // ---- band mask + per-row max (registers + shuffles + 1KB LDS) --------
    float pmax[4] = {-1e30f, -1e30f, -1e30f, -1e30f};
    #pragma unroll
    for (int t = 0; t < 5; t++) {
        if (t >= nch) break;
        int tcol = kstart + (wave + 8 * t) * 16 + fr;
        #pragma unroll
        for (int r = 0; r < 4; r++) {
            int qg = q0 + quad * 4 + r;
            bool ok = (tcol < kend) && (tcol >= qg - CWIN) && (tcol < qg + CWIN);
            float v = ok ? sreg[t][r] : -1e30f;
            sreg[t][r] = v;
            pmax[r] = fmaxf(pmax[r], v);
        }
    }
    #pragma unroll
    for (int mm = 1; mm <= 8; mm <<= 1)
        #pragma unroll
        for (int r = 0; r < 4; r++) pmax[r] = fmaxf(pmax[r], __shfl_xor(pmax[r], mm, 64));
    if (fr == 0)
        #pragma unroll
        for (int r = 0; r < 4; r++) statsA[quad * 4 + r][wave] = pmax[r];
    __syncthreads();

    float M[4];
    #pragma unroll
    for (int r = 0; r < 4; r++) {
        int row = quad * 4 + r;
        float m = statsA[row][0];
        #pragma unroll
        for (int w = 1; w < 8; w++) m = fmaxf(m, statsA[row][w]);
        M[r] = m;
    }

    // ---- exp, Pb (A-layout), row sums ------------------------------------
    float psum[4] = {};
    #pragma unroll
    for (int t = 0; t < 5; t++) {
        if (t >= nch) break;
        int colb = (wave + 8 * t) * 16 + fr;
        #pragma unroll
        for (int r = 0; r < 4; r++) {
            float p = __expf(sreg[t][r] - M[r]);   // masked: exp(-inf)=0
            psum[r] += p;
            Pb[quad * 4 + r][colb] = __float2bfloat16(p);
        }
    }
    #pragma unroll
    for (int mm = 1; mm <= 8; mm <<= 1)
        #pragma unroll
        for (int r = 0; r < 4; r++) psum[r] += __shfl_xor(psum[r], mm, 64);
    if (fr == 0)
        #pragma unroll
        for (int r = 0; r < 4; r++) statsB[quad * 4 + r][wave] = psum[r];
    __syncthreads();

    float linv[4];
    #pragma unroll
    for (int r = 0; r < 4; r++) {
        int row = quad * 4 + r;
        float s = statsB[row][0];
        #pragma unroll
        for (int w = 1; w < 8; w++) s += statsB[row][w];
        linv[r] = 1.0f / s;
    }

    // ---- PV: wave owns dims [16w,16w+16); Vt fragments from L2 -----------
    floatx4 Of = {};
    #pragma unroll
    for (int kc = 0; kc < NCH / 2; kc++) {       // 17 steps of K=32
        short8 pf = *(const short8*)&Pb[fr][kc * 32 + kg];
        const __hip_bfloat16* vrow = Vtb + (size_t)(wave * 16 + fr) * NTOK
                                   + kstart + kc * 32 + kg;
        Of = __builtin_amdgcn_mfma_f32_16x16x32_bf16(pf, *(const short8*)vrow, Of, 0, 0, 0);
    }

    // ---- u rows -> Qs overlay (A-layout for out-proj) --------------------
    {
        int col = wave * 16 + fr;
        #pragma unroll
        for (int r = 0; r < 4; r++)
            Qs[quad * 4 + r][col] = __float2bfloat16(Of[r] * linv[r]);
    }
    __syncthreads();
    short8 af2[4];
    #pragma unroll
    for (int kc = 0; kc < 4; kc++) af2[kc] = *(const short8*)&Qs[fr][kc * 32 + kg];

    // ---- out-proj: wave owns cols [128w,128w+128); Wvu from L2 -----------
    floatx4 accd[8] = {};
    #pragma unroll
    for (int n0 = 0; n0 < 8; n0++) {
        const __hip_bfloat16* wrow = Wvu + ((size_t)(wave * 128 + n0 * 16 + fr) << 7);
        #pragma unroll
        for (int kc = 0; kc < 4; kc++)
            accd[n0] = __builtin_amdgcn_mfma_f32_16x16x32_bf16(af2[kc],
                           *(const short8*)(wrow + kc * 32 + kg), accd[n0], 0, 0, 0);
    }

    // ---- norm stats from registers + paired e reads ----------------------
    float s1[4] = {}, s2[4] = {};
    #pragma unroll
    for (int n0 = 0; n0 < 8; n0++) {
        int col = wave * 128 + n0 * 16 + fr;
        #pragma unroll
        for (int r = 0; r < 4; r++) {
            float ev = e[(size_t)(q0 + quad * 4 + r) * DEMB + col];
            float od = ev + accd[n0][r];
            s1[r] += od; s2[r] += od * od;
        }
    }
    #pragma unroll
    for (int mm = 1; mm <= 8; mm <<= 1)
        #pragma unroll
        for (int r = 0; r < 4; r++) {
            s1[r] += __shfl_xor(s1[r], mm, 64);
            s2[r] += __shfl_xor(s2[r], mm, 64);
        }
    if (fr == 0)
        #pragma unroll
        for (int r = 0; r < 4; r++) {
            statsA[quad * 4 + r][wave] = s1[r];
            statsB[quad * 4 + r][wave] = s2[r];
        }
    __syncthreads();

    float im0[4], mm_[4], isd[4];
    #pragma unroll
    for (int r = 0; r < 4; r++) {
        int row = quad * 4 + r;
        float S1 = statsA[row][0], S2 = statsB[row][0];
        #pragma unroll
        for (int w = 1; w < 8; w++) { S1 += statsA[row][w]; S2 += statsB[row][w]; }
        float m0 = S1 * (1.0f / DEMB);
        float iv = 1.0f / m0;
        float m  = m0 * iv;                        // mean(out/m0), ~1
        float st = S1 * iv;                        // sum of t
        float var = (S2 * iv * iv - st * st * (1.0f / DEMB)) * (1.0f / (DEMB - 1));
        im0[r] = iv; mm_[r] = m; isd[r] = rsqrtf(var);
    }

    // ---- final: res = e + (out*im0 - m)*isd + m; write e/ebf/out ---------
    #pragma unroll
    for (int n0 = 0; n0 < 8; n0++) {
        int col = wave * 128 + n0 * 16 + fr;
        #pragma unroll
        for (int r = 0; r < 4; r++) {
            size_t idx = (size_t)(q0 + quad * 4 + r) * DEMB + col;
            float ev = e[idx];
            float t = (ev + accd[n0][r]) * im0[r];
            float res = ev + (t - mm_[r]) * isd[r] + mm_[r];
            e[idx] = res;
            ebf[idx] = __float2bfloat16(res);
            if (out_final) out_final[idx] = res * 0.125f;
        }
    }
}

extern "C" void kernel_launch(void* const* d_in, const int* in_sizes, int n_in,
                              void* d_out, int out_size, void* d_ws, size_t ws_size,
                              hipStream_t stream) {
    const float* x   = (const float*)d_in[0];
    const float* Wq  = (const float*)d_in[1];
    const float* Wk  = (const float*)d_in[2];
    const float* Wvd = (const float*)d_in[3];
    const float* Wvu = (const float*)d_in[4];

    char* ws = (char*)d_ws;
    float* e = (float*)ws;                                              // 16 MB
    __hip_bfloat16* ebf   = (__hip_bfloat16*)(ws + (16u << 20));        //  8 MB
    __hip_bfloat16* Qb    = (__hip_bfloat16*)(ws + (24u << 20));        //  1 MB
    __hip_bfloat16* Kb    = (__hip_bfloat16*)(ws + (25u << 20));        //  1 MB
    __hip_bfloat16* Vtb   = (__hip_bfloat16*)(ws + (26u << 20));        //  1 MB (+1 MB slack follows)
    __hip_bfloat16* wqkvb = (__hip_bfloat16*)(ws + (28u << 20));        //  6 MB
    __hip_bfloat16* wvub  = (__hip_bfloat16*)(ws + (34u << 20));        //  2 MB  -> 36 MB

    pack_wqkv<<<NH * QKVW * DEMB / 8 / 256, 256, 0, stream>>>(Wq, Wk, Wvd, wqkvb);
    pack_wvu<<<NH * DEMB * DH / 8 / 256, 256, 0, stream>>>(Wvu, wvub);
    init_e<<<NTOK * DEMB / 4 / 256, 256, 0, stream>>>((const float4*)x, (float4*)e, ebf);

    for (int h = 0; h < NH; h++) {
        qkv_gemm_mfma<<<dim3(QKVW / 64, NTOK / 64), 256, 0, stream>>>(
            ebf, wqkvb + (size_t)h * QKVW * DEMB, Qb, Kb, Vtb);
        attn_mega<<<NTOK / QT, 512, 0, stream>>>(
            Qb, Kb, Vtb, wvub + (size_t)h * DEMB * DH, e, ebf,
            (h == NH - 1) ? (float*)d_out : nullptr);
    }
}

// Round 8
// 454.496 us; speedup vs baseline: 18.5779x; 1.0549x over previous
//
#include <hip/hip_runtime.h>
#include <hip/hip_bf16.h>

#define NTOK 4096
#define DEMB 1024
#define NH   8
#define DH   128
#define CWIN 256
#define QKVW 384
#define SCALE 0.08838834764831845f   // 1/sqrt(128)
#define QT 16
#define NCH 34                        // 16-key chunks covering the <=527-wide band

typedef __attribute__((ext_vector_type(8))) short short8;
typedef __attribute__((ext_vector_type(4))) float floatx4;

__device__ __forceinline__ short8 pack8(float4 a, float4 b) {
    union { __hip_bfloat16 h[8]; short8 v; } o;
    o.h[0] = __float2bfloat16(a.x); o.h[1] = __float2bfloat16(a.y);
    o.h[2] = __float2bfloat16(a.z); o.h[3] = __float2bfloat16(a.w);
    o.h[4] = __float2bfloat16(b.x); o.h[5] = __float2bfloat16(b.y);
    o.h[6] = __float2bfloat16(b.z); o.h[7] = __float2bfloat16(b.w);
    return o.v;
}

// ---------------- weight prep (once per call) ----------------
__global__ void pack_wqkv(const float* __restrict__ Wq, const float* __restrict__ Wk,
                          const float* __restrict__ Wvd, __hip_bfloat16* __restrict__ dst) {
    size_t base = ((size_t)blockIdx.x * 256 + threadIdx.x) * 8;
    int k = (int)(base & 1023);
    int rh = (int)(base >> 10);
    int h = rh / QKVW;
    int row = rh - h * QKVW;
    const float* srcs[3] = {Wq, Wk, Wvd};
    const float* s = srcs[row >> 7] + (((size_t)h * DH + (row & 127)) << 10) + k;
    *(short8*)(dst + base) = pack8(*(const float4*)s, *(const float4*)(s + 4));
}

__global__ void pack_wvu(const float* __restrict__ Wvu, __hip_bfloat16* __restrict__ dst) {
    size_t base = ((size_t)blockIdx.x * 256 + threadIdx.x) * 8;
    *(short8*)(dst + base) = pack8(*(const float4*)(Wvu + base), *(const float4*)(Wvu + base + 4));
}

// ---------------- stage 0: e = x (+ bf16 mirror for head-0 qkv) -----------
__global__ void init_e(const float4* __restrict__ x, float4* __restrict__ e,
                       __hip_bfloat16* __restrict__ ebf) {
    int i = blockIdx.x * 256 + threadIdx.x;
    float4 v = x[i];
    e[i] = v;
    union { __hip_bfloat16 h[4]; uint2 u; } p;
    p.h[0] = __float2bfloat16(v.x); p.h[1] = __float2bfloat16(v.y);
    p.h[2] = __float2bfloat16(v.z); p.h[3] = __float2bfloat16(v.w);
    *(uint2*)(ebf + (size_t)i * 4) = p.u;
}

// ---------------- head-0 qkv GEMM: emits Q (scaled), K, V^T ---------------
__global__ __launch_bounds__(256) void qkv_gemm_mfma(const __hip_bfloat16* __restrict__ A,
                                                     const __hip_bfloat16* __restrict__ B,
                                                     __hip_bfloat16* __restrict__ Qb,
                                                     __hip_bfloat16* __restrict__ Kb,
                                                     __hip_bfloat16* __restrict__ Vtb) {
    constexpr int K = DEMB;
    constexpr int LDK = 40;
    const int c0 = blockIdx.x * 64, r0 = blockIdx.y * 64;
    const int tid = threadIdx.x;
    const int wave = tid >> 6, lane = tid & 63;
    const int wr = (wave >> 1) * 32, wc = (wave & 1) * 32;
    const int frow = lane & 15, kgrp = (lane >> 4) * 8;
    const int quad = lane >> 4;
    const int sr = tid >> 2, sk = (tid & 3) * 8;

    __shared__ __hip_bfloat16 As[64 * LDK];
    __shared__ __hip_bfloat16 Bs[64 * LDK];

    floatx4 acc[2][2] = {};

    for (int k0 = 0; k0 < K; k0 += 32) {
        __syncthreads();
        *(short8*)(As + sr * LDK + sk) = *(const short8*)(A + (size_t)(r0 + sr) * K + k0 + sk);
        *(short8*)(Bs + sr * LDK + sk) = *(const short8*)(B + (size_t)(c0 + sr) * K + k0 + sk);
        __syncthreads();
        short8 a0 = *(const short8*)(As + (wr + frow) * LDK + kgrp);
        short8 a1 = *(const short8*)(As + (wr + 16 + frow) * LDK + kgrp);
        short8 b0 = *(const short8*)(Bs + (wc + frow) * LDK + kgrp);
        short8 b1 = *(const short8*)(Bs + (wc + 16 + frow) * LDK + kgrp);
        acc[0][0] = __builtin_amdgcn_mfma_f32_16x16x32_bf16(a0, b0, acc[0][0], 0, 0, 0);
        acc[0][1] = __builtin_amdgcn_mfma_f32_16x16x32_bf16(a0, b1, acc[0][1], 0, 0, 0);
        acc[1][0] = __builtin_amdgcn_mfma_f32_16x16x32_bf16(a1, b0, acc[1][0], 0, 0, 0);
        acc[1][1] = __builtin_amdgcn_mfma_f32_16x16x32_bf16(a1, b1, acc[1][1], 0, 0, 0);
    }

    #pragma unroll
    for (int i = 0; i < 2; i++)
        #pragma unroll
        for (int j = 0; j < 2; j++) {
            int col = c0 + wc + j * 16 + frow;
            int row0 = r0 + wr + i * 16 + quad * 4;
            if (col < DH) {
                #pragma unroll
                for (int r = 0; r < 4; r++)
                    Qb[(size_t)(row0 + r) * DH + col] = __float2bfloat16(acc[i][j][r] * SCALE);
            } else if (col < 2 * DH) {
                #pragma unroll
                for (int r = 0; r < 4; r++)
                    Kb[(size_t)(row0 + r) * DH + col - DH] = __float2bfloat16(acc[i][j][r]);
            } else {
                union { __hip_bfloat16 h[4]; uint2 u; } p;
                #pragma unroll
                for (int r = 0; r < 4; r++) p.h[r] = __float2bfloat16(acc[i][j][r]);
                *(uint2*)(Vtb + (size_t)(col - 2 * DH) * NTOK + row0) = p.u;
            }
        }
}

// ---------------- fused head kernel -----------------------------------
// grid 256 (16 queries/block), 8 waves. Flash attention (single-pass
// softmax, fragments from L2) + out-proj + residual/double-norm + FUSED
// next-head QKV for the block's own 16 rows (row-local GEMM, Wqkv from L2).
// Next-head Q/K/Vt go to the ping-pong buffers (no cross-head race).
// OOB band-edge fragment reads land in adjacent ws buffers: finite bf16,
// multiplied by p=0.
__global__ __launch_bounds__(512) void attn_head(const __hip_bfloat16* __restrict__ Qb,
                                                 const __hip_bfloat16* __restrict__ Kb,
                                                 const __hip_bfloat16* __restrict__ Vtb,
                                                 __hip_bfloat16* __restrict__ Qn,
                                                 __hip_bfloat16* __restrict__ Kn,
                                                 __hip_bfloat16* __restrict__ Vtn,
                                                 const __hip_bfloat16* __restrict__ Wqkv_nxt,
                                                 const __hip_bfloat16* __restrict__ Wvu,
                                                 float* __restrict__ e,
                                                 float* __restrict__ out_final) {
    const int q0 = blockIdx.x * QT;
    const int tid = threadIdx.x;
    const int wave = tid >> 6, lane = tid & 63;
    const int fr = lane & 15, kg = (lane >> 4) * 8;
    const int quad = lane >> 4;
    const bool last = (out_final != nullptr);

    __shared__ alignas(16) __hip_bfloat16 Qs[QT][DH + 8];      // Q tile; later u rows
    __shared__ alignas(16) __hip_bfloat16 Pb[QT][NCH * 16 + 8];
    __shared__ alignas(16) __hip_bfloat16 Ebs[QT][DEMB + 8];   // bf16 res rows (A for qkv tail)
    __shared__ float statsA[QT][8];
    __shared__ float statsB[QT][8];

    if (tid < 256) {   // stage Q (16x128 bf16, pre-scaled)
        int r = tid >> 4, c8 = (tid & 15) * 8;
        *(short8*)&Qs[r][c8] = *(const short8*)(Qb + (size_t)(q0 + r) * DH + c8);
    }
    __syncthreads();
    short8 af[4];
    #pragma unroll
    for (int kc = 0; kc < 4; kc++) af[kc] = *(const short8*)&Qs[fr][kc * 32 + kg];

    const int kstart = max(q0 - CWIN, 0);
    const int kend   = min(q0 + QT - 1 + CWIN + 1, NTOK);
    const int nch = (wave < 2) ? 5 : 4;   // chunks ch = wave + 8t, ch < 34

    // ---- scores: wave's chunks, K fragments straight from L2 -------------
    floatx4 sreg[5];
    #pragma unroll
    for (int t = 0; t < 5; t++) {
        if (t >= nch) break;
        int ch = wave + 8 * t;
        const __hip_bfloat16* krow = Kb + (size_t)(kstart + ch * 16 + fr) * DH;
        floatx4 s = {};
        #pragma unroll
        for (int kc = 0; kc < 4; kc++)
            s = __builtin_amdgcn_mfma_f32_16x16x32_bf16(af[kc],
                    *(const short8*)(krow + kc * 32 + kg), s, 0, 0, 0);
        sreg[t] = s;
    }

    // ---- band mask + per-row max ------------------------------------------
    float pmax[4] = {-1e30f, -1e30f, -1e30f, -1e30f};
    #pragma unroll
    for (int t = 0; t < 5; t++) {
        if (t >= nch) break;
        int tcol = kstart + (wave + 8 * t) * 16 + fr;
        #pragma unroll
        for (int r = 0; r < 4; r++) {
            int qg = q0 + quad * 4 + r;
            bool ok = (tcol < kend) && (tcol >= qg - CWIN) && (tcol < qg + CWIN);
            float v = ok ? sreg[t][r] : -1e30f;
            sreg[t][r] = v;
            pmax[r] = fmaxf(pmax[r], v);
        }
    }
    #pragma unroll
    for (int mm = 1; mm <= 8; mm <<= 1)
        #pragma unroll
        for (int r = 0; r < 4; r++) pmax[r] = fmaxf(pmax[r], __shfl_xor(pmax[r], mm, 64));
    if (fr == 0)
        #pragma unroll
        for (int r = 0; r < 4; r++) statsA[quad * 4 + r][wave] = pmax[r];
    __syncthreads();

    float M[4];
    #pragma unroll
    for (int r = 0; r < 4; r++) {
        int row = quad * 4 + r;
        float m = statsA[row][0];
        #pragma unroll
        for (int w = 1; w < 8; w++) m = fmaxf(m, statsA[row][w]);
        M[r] = m;
    }

    // ---- exp -> Pb (A-layout), row sums -----------------------------------
    float psum[4] = {};
    #pragma unroll
    for (int t = 0; t < 5; t++) {
        if (t >= nch) break;
        int colb = (wave + 8 * t) * 16 + fr;
        #pragma unroll
        for (int r = 0; r < 4; r++) {
            float p = __expf(sreg[t][r] - M[r]);
            psum[r] += p;
            Pb[quad * 4 + r][colb] = __float2bfloat16(p);
        }
    }
    #pragma unroll
    for (int mm = 1; mm <= 8; mm <<= 1)
        #pragma unroll
        for (int r = 0; r < 4; r++) psum[r] += __shfl_xor(psum[r], mm, 64);
    if (fr == 0)
        #pragma unroll
        for (int r = 0; r < 4; r++) statsB[quad * 4 + r][wave] = psum[r];
    __syncthreads();

    float linv[4];
    #pragma unroll
    for (int r = 0; r < 4; r++) {
        int row = quad * 4 + r;
        float s = statsB[row][0];
        #pragma unroll
        for (int w = 1; w < 8; w++) s += statsB[row][w];
        linv[r] = 1.0f / s;
    }

    // ---- PV: wave owns dims [16w,16w+16); Vt fragments from L2 ------------
    floatx4 Of = {};
    #pragma unroll
    for (int kc = 0; kc < NCH / 2; kc++) {
        short8 pf = *(const short8*)&Pb[fr][kc * 32 + kg];
        const __hip_bfloat16* vrow = Vtb + (size_t)(wave * 16 + fr) * NTOK
                                   + kstart + kc * 32 + kg;
        Of = __builtin_amdgcn_mfma_f32_16x16x32_bf16(pf, *(const short8*)vrow, Of, 0, 0, 0);
    }

    // ---- u rows -> Qs overlay (A-layout for out-proj) ---------------------
    {
        int col = wave * 16 + fr;
        #pragma unroll
        for (int r = 0; r < 4; r++)
            Qs[quad * 4 + r][col] = __float2bfloat16(Of[r] * linv[r]);
    }
    __syncthreads();
    short8 af2[4];
    #pragma unroll
    for (int kc = 0; kc < 4; kc++) af2[kc] = *(const short8*)&Qs[fr][kc * 32 + kg];

    // ---- out-proj: wave owns cols [128w,128w+128); Wvu from L2 ------------
    floatx4 accd[8] = {};
    #pragma unroll
    for (int n0 = 0; n0 < 8; n0++) {
        const __hip_bfloat16* wrow = Wvu + ((size_t)(wave * 128 + n0 * 16 + fr) << 7);
        #pragma unroll
        for (int kc = 0; kc < 4; kc++)
            accd[n0] = __builtin_amdgcn_mfma_f32_16x16x32_bf16(af2[kc],
                           *(const short8*)(wrow + kc * 32 + kg), accd[n0], 0, 0, 0);
    }

    // ---- norm stats (e rows kept in registers) ----------------------------
    floatx4 eo8[8];
    float s1[4] = {}, s2[4] = {};
    #pragma unroll
    for (int n0 = 0; n0 < 8; n0++) {
        int col = wave * 128 + n0 * 16 + fr;
        #pragma unroll
        for (int r = 0; r < 4; r++) {
            float ev = e[(size_t)(q0 + quad * 4 + r) * DEMB + col];
            eo8[n0][r] = ev;
            float od = ev + accd[n0][r];
            s1[r] += od; s2[r] += od * od;
        }
    }
    #pragma unroll
    for (int mm = 1; mm <= 8; mm <<= 1)
        #pragma unroll
        for (int r = 0; r < 4; r++) {
            s1[r] += __shfl_xor(s1[r], mm, 64);
            s2[r] += __shfl_xor(s2[r], mm, 64);
        }
    if (fr == 0)
        #pragma unroll
        for (int r = 0; r < 4; r++) {
            statsA[quad * 4 + r][wave] = s1[r];
            statsB[quad * 4 + r][wave] = s2[r];
        }
    __syncthreads();

    float im0[4], mm_[4], isd[4];
    #pragma unroll
    for (int r = 0; r < 4; r++) {
        int row = quad * 4 + r;
        float S1 = statsA[row][0], S2 = statsB[row][0];
        #pragma unroll
        for (int w = 1; w < 8; w++) { S1 += statsA[row][w]; S2 += statsB[row][w]; }
        float m0 = S1 * (1.0f / DEMB);
        float iv = 1.0f / m0;
        float m  = m0 * iv;                        // mean(out/m0) ~ 1
        float st = S1 * iv;
        float var = (S2 * iv * iv - st * st * (1.0f / DEMB)) * (1.0f / (DEMB - 1));
        im0[r] = iv; mm_[r] = m; isd[r] = rsqrtf(var);
    }

    // ---- final residual+norm; write e (or out); stage bf16 res for tail ---
    #pragma unroll
    for (int n0 = 0; n0 < 8; n0++) {
        int col = wave * 128 + n0 * 16 + fr;
        #pragma unroll
        for (int r = 0; r < 4; r++) {
            float ev = eo8[n0][r];
            float t = (ev + accd[n0][r]) * im0[r];
            float res = ev + (t - mm_[r]) * isd[r] + mm_[r];
            size_t idx = (size_t)(q0 + quad * 4 + r) * DEMB + col;
            if (last) {
                out_final[idx] = res * 0.125f;
            } else {
                e[idx] = res;
                Ebs[quad * 4 + r][col] = __float2bfloat16(res);
            }
        }
    }

    // ---- fused next-head QKV: 24 N-tiles over 8 waves (3 each) ------------
    if (!last) {
        __syncthreads();               // Ebs complete
        floatx4 acc3[3] = {};
        const int n0t = 3 * wave;
        const __hip_bfloat16* wbase = Wqkv_nxt + (size_t)(n0t * 16 + fr) * DEMB + kg;
        #pragma unroll 8
        for (int kc = 0; kc < 32; kc++) {
            short8 a = *(const short8*)&Ebs[fr][kc * 32 + kg];
            #pragma unroll
            for (int t = 0; t < 3; t++)
                acc3[t] = __builtin_amdgcn_mfma_f32_16x16x32_bf16(a,
                              *(const short8*)(wbase + (size_t)t * 16 * DEMB + kc * 32),
                              acc3[t], 0, 0, 0);
        }
        const int row0 = q0 + quad * 4;
        #pragma unroll
        for (int t = 0; t < 3; t++) {
            int n = n0t + t;
            if (n < 8) {               // Q, pre-scaled
                int col = n * 16 + fr;
                #pragma unroll
                for (int rr = 0; rr < 4; rr++)
                    Qn[(size_t)(row0 + rr) * DH + col] = __float2bfloat16(acc3[t][rr] * SCALE);
            } else if (n < 16) {       // K
                int col = (n - 8) * 16 + fr;
                #pragma unroll
                for (int rr = 0; rr < 4; rr++)
                    Kn[(size_t)(row0 + rr) * DH + col] = __float2bfloat16(acc3[t][rr]);
            } else {                   // V^T
                int d = (n - 16) * 16 + fr;
                union { __hip_bfloat16 h[4]; uint2 u; } p;
                #pragma unroll
                for (int rr = 0; rr < 4; rr++) p.h[rr] = __float2bfloat16(acc3[t][rr]);
                *(uint2*)(Vtn + (size_t)d * NTOK + row0) = p.u;
            }
        }
    }
}

extern "C" void kernel_launch(void* const* d_in, const int* in_sizes, int n_in,
                              void* d_out, int out_size, void* d_ws, size_t ws_size,
                              hipStream_t stream) {
    const float* x   = (const float*)d_in[0];
    const float* Wq  = (const float*)d_in[1];
    const float* Wk  = (const float*)d_in[2];
    const float* Wvd = (const float*)d_in[3];
    const float* Wvu = (const float*)d_in[4];

    char* ws = (char*)d_ws;
    float* e = (float*)ws;                                              // 16 MB
    __hip_bfloat16* ebf   = (__hip_bfloat16*)(ws + (16u << 20));        //  8 MB (head-0 prologue only)
    __hip_bfloat16* Qb[2] = {(__hip_bfloat16*)(ws + (24u << 20)),
                             (__hip_bfloat16*)(ws + (27u << 20))};      //  1 MB each
    __hip_bfloat16* Kb[2] = {(__hip_bfloat16*)(ws + (25u << 20)),
                             (__hip_bfloat16*)(ws + (28u << 20))};
    __hip_bfloat16* Vt[2] = {(__hip_bfloat16*)(ws + (26u << 20)),
                             (__hip_bfloat16*)(ws + (29u << 20))};
    __hip_bfloat16* wqkvb = (__hip_bfloat16*)(ws + (30u << 20));        //  6 MB
    __hip_bfloat16* wvub  = (__hip_bfloat16*)(ws + (36u << 20));        //  2 MB  -> 38 MB

    pack_wqkv<<<NH * QKVW * DEMB / 8 / 256, 256, 0, stream>>>(Wq, Wk, Wvd, wqkvb);
    pack_wvu<<<NH * DEMB * DH / 8 / 256, 256, 0, stream>>>(Wvu, wvub);
    init_e<<<NTOK * DEMB / 4 / 256, 256, 0, stream>>>((const float4*)x, (float4*)e, ebf);

    qkv_gemm_mfma<<<dim3(QKVW / 64, NTOK / 64), 256, 0, stream>>>(
        ebf, wqkvb, Qb[0], Kb[0], Vt[0]);

    for (int h = 0; h < NH; h++) {
        int cur = h & 1, nxt = 1 - cur;
        attn_head<<<NTOK / QT, 512, 0, stream>>>(
            Qb[cur], Kb[cur], Vt[cur],
            Qb[nxt], Kb[nxt], Vt[nxt],
            wqkvb + (size_t)((h + 1 < NH) ? h + 1 : 0) * QKVW * DEMB,
            wvub + (size_t)h * DEMB * DH, e,
            (h == NH - 1) ? (float*)d_out : nullptr);
    }
}